// Round 1
// baseline (14401.175 us; speedup 1.0000x reference)
//
#include <hip/hip_runtime.h>

// BidirectionalRNN on MI355X — persistent-kernel design, round 1.
// Phases: weight-split/transpose -> proj0 (MFMA split-bf16 3-pass) -> recurrence A
// (fwd||bwd, 16 WGs each, per-step atomic group barrier) -> proj1 -> recurrence B
// -> finals + FC.  All barriers are monotonic atomic counters zeroed by rnn_init
// (launched first on the stream every call; graph keeps the order).
// ws requirement ~139 MB.

typedef unsigned short u16;
typedef unsigned int u32;
typedef __attribute__((ext_vector_type(8))) short short8;
typedef __attribute__((ext_vector_type(4))) float f32x4;

#define DEV static __device__ __forceinline__

DEV u16 f2bf(float f) {                       // f32 -> bf16 RNE
  u32 u = __builtin_bit_cast(u32, f);
  u = (u + 0x7fffu + ((u >> 16) & 1u)) >> 16;
  return (u16)u;
}
DEV float bf2f(u16 h) { return __builtin_bit_cast(float, ((u32)h) << 16); }

DEV f32x4 MFMA(short8 a, short8 b, f32x4 c) {
  return __builtin_amdgcn_mfma_f32_16x16x32_bf16(a, b, c, 0, 0, 0);
}

// ---------------- ws layout (bytes) ----------------
constexpr size_t OFF_CNT  = 0;                       // 1024 B of counters
constexpr size_t OFF_WT0F = 1024;
constexpr size_t NE_WT0   = 512 * 1024;              // elements per plane (W^T [512][1024])
constexpr size_t SZ_WT0   = NE_WT0 * 2 * 2;          // hi+lo
constexpr size_t OFF_WT0B = OFF_WT0F + SZ_WT0;
constexpr size_t OFF_WT1F = OFF_WT0B + SZ_WT0;
constexpr size_t NE_WT1   = 512 * 1536;              // W^T [512][1536]
constexpr size_t SZ_WT1   = NE_WT1 * 2 * 2;
constexpr size_t OFF_WT1B = OFF_WT1F + SZ_WT1;
constexpr size_t OFF_XWF  = OFF_WT1B + SZ_WT1;       // f32 [512][32][512]
constexpr size_t SZ_XW    = 16384ull * 512 * 4;
constexpr size_t OFF_XWB  = OFF_XWF + SZ_XW;
constexpr size_t OFF_Y0   = OFF_XWB + SZ_XW;         // f32 [512][32][1024]
constexpr size_t SZ_Y0    = 16384ull * 1024 * 4;
constexpr size_t OFF_H    = OFF_Y0 + SZ_Y0;          // 4 dl x (hi buf0,buf1 | lo buf0,buf1) x 16384 u16

template<int SLP>
DEV void barrier_at(u32* c, u32 target) {
  __syncthreads();
  if (threadIdx.x == 0) {
    __hip_atomic_fetch_add(c, 1u, __ATOMIC_ACQ_REL, __HIP_MEMORY_SCOPE_AGENT);
    while (__hip_atomic_load(c, __ATOMIC_ACQUIRE, __HIP_MEMORY_SCOPE_AGENT) < target) {
      __builtin_amdgcn_s_sleep(SLP);
    }
  }
  __syncthreads();
}

// ---------------- projection GEMM: C[16384][512] = A[16384][K] @ W + bias ----------------
// A: f32 row-major, row r maps to x-row ((r&31)*512 + (r>>5)) when perm (layer 0).
// B: pre-transposed bf16 hi/lo planes wt[n][r], pitch bpitch, K-rows start at bkoff.
// 3-pass split: hi*hi + hi*lo + lo*hi.
DEV void proj_phase(const float* __restrict__ A, bool perm, int bpitch, int bkoff, int K,
                    const u16* __restrict__ wfh, const u16* __restrict__ wfl,
                    const u16* __restrict__ wbh, const u16* __restrict__ wbl,
                    const float* __restrict__ biasF, const float* __restrict__ biasB,
                    float* __restrict__ Cf, float* __restrict__ Cb,
                    u16* aHi, u16* aLo, u16* bHi, u16* bLo) {
  const int tid = threadIdx.x;
  const int l = tid & 63, w = tid >> 6;
  const int lr = l & 15, lk = (l >> 4) * 8;
  const int wm = (w >> 1) * 64, wn = (w & 1) * 64;
  for (int t = blockIdx.x; t < 1024; t += 256) {
    const int dir = t >> 9, tile = t & 511;
    const int mbase = (tile >> 2) * 128, nbase = (tile & 3) * 128;
    const u16* bh_src = dir ? wbh : wfh;
    const u16* bl_src = dir ? wbl : wfl;
    const float* bias = dir ? biasB : biasF;
    float* C = dir ? Cb : Cf;
    f32x4 acc[4][4] = {};
    for (int kk = 0; kk < K; kk += 32) {
      {  // stage A (f32 -> hi/lo bf16) and B (pre-split) into LDS, [128][40] padded
        const int row = tid >> 1, half = tid & 1;
        const int r = mbase + row;
        const int srcRow = perm ? (((r & 31) << 9) + (r >> 5)) : r;
        const float* ap = A + (size_t)srcRow * K + kk + half * 16;
        f32x4 q0 = *(const f32x4*)(ap + 0);
        f32x4 q1 = *(const f32x4*)(ap + 4);
        f32x4 q2 = *(const f32x4*)(ap + 8);
        f32x4 q3 = *(const f32x4*)(ap + 12);
        short8 h0, l0, h1, l1;
        #pragma unroll
        for (int e = 0; e < 4; ++e) {
          { float v = q0[e]; u16 hv = f2bf(v); h0[e]   = (short)hv; l0[e]   = (short)f2bf(v - bf2f(hv)); }
          { float v = q1[e]; u16 hv = f2bf(v); h0[e+4] = (short)hv; l0[e+4] = (short)f2bf(v - bf2f(hv)); }
          { float v = q2[e]; u16 hv = f2bf(v); h1[e]   = (short)hv; l1[e]   = (short)f2bf(v - bf2f(hv)); }
          { float v = q3[e]; u16 hv = f2bf(v); h1[e+4] = (short)hv; l1[e+4] = (short)f2bf(v - bf2f(hv)); }
        }
        const int o = row * 40 + half * 16;
        *(short8*)&aHi[o] = h0; *(short8*)&aHi[o + 8] = h1;
        *(short8*)&aLo[o] = l0; *(short8*)&aLo[o + 8] = l1;
        const size_t bo = (size_t)(nbase + row) * bpitch + bkoff + kk + half * 16;
        *(short8*)&bHi[o]     = *(const short8*)&bh_src[bo];
        *(short8*)&bHi[o + 8] = *(const short8*)&bh_src[bo + 8];
        *(short8*)&bLo[o]     = *(const short8*)&bl_src[bo];
        *(short8*)&bLo[o + 8] = *(const short8*)&bl_src[bo + 8];
      }
      __syncthreads();
      short8 afh[4], afl[4], bfh[4], bfl[4];
      #pragma unroll
      for (int i = 0; i < 4; ++i) {
        afh[i] = *(short8*)&aHi[(wm + i * 16 + lr) * 40 + lk];
        afl[i] = *(short8*)&aLo[(wm + i * 16 + lr) * 40 + lk];
        bfh[i] = *(short8*)&bHi[(wn + i * 16 + lr) * 40 + lk];
        bfl[i] = *(short8*)&bLo[(wn + i * 16 + lr) * 40 + lk];
      }
      #pragma unroll
      for (int i = 0; i < 4; ++i)
        #pragma unroll
        for (int j = 0; j < 4; ++j) {
          acc[i][j] = MFMA(afh[i], bfh[j], acc[i][j]);
          acc[i][j] = MFMA(afh[i], bfl[j], acc[i][j]);
          acc[i][j] = MFMA(afl[i], bfh[j], acc[i][j]);
        }
      __syncthreads();
    }
    #pragma unroll
    for (int i = 0; i < 4; ++i)
      #pragma unroll
      for (int j = 0; j < 4; ++j) {
        const int gcol = nbase + wn + j * 16 + lr;
        const float bv = bias[gcol];
        #pragma unroll
        for (int rr = 0; rr < 4; ++rr) {
          const int grow = mbase + wm + i * 16 + (l >> 4) * 4 + rr;
          C[(size_t)grow * 512 + gcol] = acc[i][j][rr] + bv;
        }
      }
  }
}

// ---------------- recurrence: 512 steps of h = tanh(xw[s] + h @ Wh) ----------------
// 16 WGs per direction; WG `slot` owns output cols [slot*32, slot*32+32).
// Wave w holds Wh fragments for K-chunk [w*128,(w+1)*128) in VGPRs (hi/lo),
// computes partial acc for all four 16x16 tiles, LDS-reduces across waves,
// then wave w finishes tile w. h state: bf16 hi/lo planes [32][512], double-buffered.
DEV void recurrence(bool fwd, const float* __restrict__ xw,
                    const u16* __restrict__ wtHi, const u16* __restrict__ wtLo,
                    int wpitch, int wkoff,
                    u16* __restrict__ hHi, u16* __restrict__ hLo,
                    float* __restrict__ y0, int ycol0,
                    u32* gc, int slot, float* red) {
  const int l = threadIdx.x & 63, w = threadIdx.x >> 6;
  const int lr = l & 15, lk4 = l >> 4;
  const int j0 = slot * 32;
  short8 bh[2][4], bl[2][4];
  #pragma unroll
  for (int nt = 0; nt < 2; ++nt)
    #pragma unroll
    for (int ks = 0; ks < 4; ++ks) {
      const int col = j0 + nt * 16 + lr;
      const int k = w * 128 + ks * 32 + lk4 * 8;
      bh[nt][ks] = *(const short8*)&wtHi[(size_t)col * wpitch + wkoff + k];
      bl[nt][ks] = *(const short8*)&wtLo[(size_t)col * wpitch + wkoff + k];
    }
  const int mrow = (w >> 1) * 16 + lk4 * 4;
  const int ncol = j0 + (w & 1) * 16 + lr;
  for (int t = 0; t < 512; ++t) {
    const int s = fwd ? t : (511 - t);
    const u16* hh = hHi + (t & 1) * 16384;
    const u16* hl = hLo + (t & 1) * 16384;
    u16* nhh = hHi + ((t & 1) ^ 1) * 16384;
    u16* nhl = hLo + ((t & 1) ^ 1) * 16384;
    f32x4 acc[2][2] = {};
    #pragma unroll
    for (int ks = 0; ks < 4; ++ks) {
      const int k = w * 128 + ks * 32 + lk4 * 8;
      short8 a0h = *(const short8*)&hh[lr * 512 + k];
      short8 a1h = *(const short8*)&hh[(16 + lr) * 512 + k];
      short8 a0l = *(const short8*)&hl[lr * 512 + k];
      short8 a1l = *(const short8*)&hl[(16 + lr) * 512 + k];
      #pragma unroll
      for (int nt = 0; nt < 2; ++nt) {
        acc[0][nt] = MFMA(a0h, bh[nt][ks], acc[0][nt]);
        acc[0][nt] = MFMA(a0h, bl[nt][ks], acc[0][nt]);
        acc[0][nt] = MFMA(a0l, bh[nt][ks], acc[0][nt]);
        acc[1][nt] = MFMA(a1h, bh[nt][ks], acc[1][nt]);
        acc[1][nt] = MFMA(a1h, bl[nt][ks], acc[1][nt]);
        acc[1][nt] = MFMA(a1l, bh[nt][ks], acc[1][nt]);
      }
    }
    #pragma unroll
    for (int t4 = 0; t4 < 4; ++t4)
      *(f32x4*)&red[((w * 4 + t4) * 64 + l) * 4] = acc[t4 >> 1][t4 & 1];
    __syncthreads();
    f32x4 fin = *(const f32x4*)&red[((0 * 4 + w) * 64 + l) * 4];
    #pragma unroll
    for (int pw = 1; pw < 4; ++pw)
      fin += *(const f32x4*)&red[((pw * 4 + w) * 64 + l) * 4];
    #pragma unroll
    for (int rr = 0; rr < 4; ++rr) {
      const int row = mrow + rr;
      const float pre = xw[(size_t)(s * 32 + row) * 512 + ncol] + fin[rr];
      const float v = tanhf(pre);
      const u16 hv = f2bf(v);
      const u16 lv = f2bf(v - bf2f(hv));
      nhh[row * 512 + ncol] = hv;
      nhl[row * 512 + ncol] = lv;
      if (y0) y0[(size_t)(s * 32 + row) * 1024 + ycol0 + ncol] = v;
    }
    barrier_at<1>(gc, (u32)(t + 1) * 16);
  }
}

__global__ void rnn_init(u32* c) { c[threadIdx.x] = 0; }

__global__ __launch_bounds__(256, 1) void rnn_main(
    const float* __restrict__ x,
    const float* __restrict__ Wf0, const float* __restrict__ bf0,
    const float* __restrict__ Wb0, const float* __restrict__ bb0,
    const float* __restrict__ Wf1, const float* __restrict__ bf1,
    const float* __restrict__ Wb1, const float* __restrict__ bb1,
    const float* __restrict__ Wfc, const float* __restrict__ bfc,
    float* __restrict__ out, char* __restrict__ ws) {
  __shared__ __align__(16) u16 lds[20480];          // 40 KB: proj tiles / rec reduce
  u16* aHi = lds; u16* aLo = lds + 5120; u16* bHi = lds + 10240; u16* bLo = lds + 15360;
  float* red = (float*)lds;

  u32* cnt = (u32*)(ws + OFF_CNT);
  u16* wt0f_hi = (u16*)(ws + OFF_WT0F); u16* wt0f_lo = wt0f_hi + NE_WT0;
  u16* wt0b_hi = (u16*)(ws + OFF_WT0B); u16* wt0b_lo = wt0b_hi + NE_WT0;
  u16* wt1f_hi = (u16*)(ws + OFF_WT1F); u16* wt1f_lo = wt1f_hi + NE_WT1;
  u16* wt1b_hi = (u16*)(ws + OFF_WT1B); u16* wt1b_lo = wt1b_hi + NE_WT1;
  float* xwf = (float*)(ws + OFF_XWF);
  float* xwb = (float*)(ws + OFF_XWB);
  float* y0  = (float*)(ws + OFF_Y0);
  u16* hb = (u16*)(ws + OFF_H);

  const int gtid = blockIdx.x * 256 + threadIdx.x;

  // ---- init: split+transpose weights, zero h state ----
  for (u32 j = gtid; j < (u32)NE_WT0; j += 65536u) {
    const u32 n = j >> 10, r = j & 1023;
    float v = Wf0[(size_t)r * 512 + n];
    u16 hv = f2bf(v); wt0f_hi[j] = hv; wt0f_lo[j] = f2bf(v - bf2f(hv));
    v = Wb0[(size_t)r * 512 + n];
    hv = f2bf(v); wt0b_hi[j] = hv; wt0b_lo[j] = f2bf(v - bf2f(hv));
  }
  for (u32 j = gtid; j < (u32)NE_WT1; j += 65536u) {
    const u32 n = j / 1536u, r = j - n * 1536u;
    float v = Wf1[(size_t)r * 512 + n];
    u16 hv = f2bf(v); wt1f_hi[j] = hv; wt1f_lo[j] = f2bf(v - bf2f(hv));
    v = Wb1[(size_t)r * 512 + n];
    hv = f2bf(v); wt1b_hi[j] = hv; wt1b_lo[j] = f2bf(v - bf2f(hv));
  }
  for (u32 j = gtid; j < 131072u; j += 65536u) ((u32*)hb)[j] = 0;

  u32 ep = 0;
  barrier_at<4>(cnt, (++ep) * 256);

  // ---- layer-0 input projection ----
  proj_phase(x, true, 1024, 0, 512, wt0f_hi, wt0f_lo, wt0b_hi, wt0b_lo,
             bf0, bb0, xwf, xwb, aHi, aLo, bHi, bLo);
  barrier_at<4>(cnt, (++ep) * 256);

  const int bid = blockIdx.x;
  const int slot = bid >> 3;
  const bool rf = (bid < 128) && ((bid & 7) == 0);   // 16 WGs (XCD-local heuristic)
  const bool rb = (bid < 128) && ((bid & 7) == 1);   // 16 WGs

  // ---- layer-0 recurrence (fwd || bwd), writes y0 ----
  if (rf)      recurrence(true,  xwf, wt0f_hi, wt0f_lo, 1024, 512,
                          hb + 0 * 65536, hb + 0 * 65536 + 32768, y0, 0,   cnt + 16, slot, red);
  else if (rb) recurrence(false, xwb, wt0b_hi, wt0b_lo, 1024, 512,
                          hb + 1 * 65536, hb + 1 * 65536 + 32768, y0, 512, cnt + 32, slot, red);
  barrier_at<32>(cnt, (++ep) * 256);

  // ---- layer-1 input projection (A = y0, K=1024) ----
  proj_phase(y0, false, 1536, 0, 1024, wt1f_hi, wt1f_lo, wt1b_hi, wt1b_lo,
             bf1, bb1, xwf, xwb, aHi, aLo, bHi, bLo);
  barrier_at<4>(cnt, (++ep) * 256);

  // ---- layer-1 recurrence ----
  if (rf)      recurrence(true,  xwf, wt1f_hi, wt1f_lo, 1536, 1024,
                          hb + 2 * 65536, hb + 2 * 65536 + 32768, nullptr, 0, cnt + 48, slot, red);
  else if (rb) recurrence(false, xwb, wt1b_hi, wt1b_lo, 1536, 1024,
                          hb + 3 * 65536, hb + 3 * 65536 + 32768, nullptr, 0, cnt + 64, slot, red);
  barrier_at<32>(cnt, (++ep) * 256);

  // ---- finals: hf0,hf1,hb0,hb1 -> d_out (states live in buf0 after 512 steps) ----
  {
    const int i = gtid;                 // 65536 values exactly
    const int dl = i >> 14, idx = i & 16383;
    const u16* hh = hb + dl * 65536;
    const u16* hl = hh + 32768;
    const float v = bf2f(hh[idx]) + bf2f(hl[idx]);
    const int base = 8192 + ((dl & 1) ? 32768 : 0) + ((dl >> 1) ? 16384 : 0);
    out[base + idx] = v;
  }
  // ---- FC: logits = [hf1|hb1] @ Wfc + bfc ----
  if (bid < 32) {
    const int gid = gtid;
    const int b = gid >> 8, o = gid & 255;
    const u16* f1h = hb + 2 * 65536; const u16* f1l = f1h + 32768;
    const u16* b1h = hb + 3 * 65536; const u16* b1l = b1h + 32768;
    float a = bfc[o];
    for (int k = 0; k < 512; ++k)
      a += (bf2f(f1h[b * 512 + k]) + bf2f(f1l[b * 512 + k])) * Wfc[(size_t)k * 256 + o];
    for (int k = 0; k < 512; ++k)
      a += (bf2f(b1h[b * 512 + k]) + bf2f(b1l[b * 512 + k])) * Wfc[(size_t)(512 + k) * 256 + o];
    out[gid] = a;
  }
}

extern "C" void kernel_launch(void* const* d_in, const int* in_sizes, int n_in,
                              void* d_out, int out_size, void* d_ws, size_t ws_size,
                              hipStream_t stream) {
  (void)in_sizes; (void)n_in; (void)out_size; (void)ws_size;
  const float* x   = (const float*)d_in[0];
  const float* Wf0 = (const float*)d_in[1];
  const float* bf0 = (const float*)d_in[2];
  const float* Wb0 = (const float*)d_in[3];
  const float* bb0 = (const float*)d_in[4];
  const float* Wf1 = (const float*)d_in[5];
  const float* bf1 = (const float*)d_in[6];
  const float* Wb1 = (const float*)d_in[7];
  const float* bb1 = (const float*)d_in[8];
  const float* Wfc = (const float*)d_in[9];
  const float* bfc = (const float*)d_in[10];
  rnn_init<<<1, 256, 0, stream>>>((u32*)d_ws);
  rnn_main<<<256, 256, 0, stream>>>(x, Wf0, bf0, Wb0, bb0, Wf1, bf1, Wb1, bb1,
                                    Wfc, bfc, (float*)d_out, (char*)d_ws);
}

// Round 2
// 6339.244 us; speedup vs baseline: 2.2717x; 2.2717x over previous
//
#include <hip/hip_runtime.h>

// BidirectionalRNN on MI355X — round 2: fence-free per-step sync.
// h exchanged via sc0sc1 (coherence-point) loads/stores + per-wave tags;
// phase barriers use relaxed polling with a single release/acquire per WG.

typedef unsigned short u16;
typedef unsigned int u32;
typedef __attribute__((ext_vector_type(8))) short short8;
typedef __attribute__((ext_vector_type(4))) float f32x4;

#define DEV static __device__ __forceinline__

DEV u16 f2bf(float f) {                       // f32 -> bf16 RNE
  u32 u = __builtin_bit_cast(u32, f);
  u = (u + 0x7fffu + ((u >> 16) & 1u)) >> 16;
  return (u16)u;
}
DEV float bf2f(u16 h) { return __builtin_bit_cast(float, ((u32)h) << 16); }

DEV f32x4 MFMA(short8 a, short8 b, f32x4 c) {
  return __builtin_amdgcn_mfma_f32_16x16x32_bf16(a, b, c, 0, 0, 0);
}

// ---- coherence-point (bypass L1/L2) access helpers ----
DEV short8 ld_b128_coh(const u16* p) {        // issue only; caller must vm_drain before use
  short8 r;
  asm volatile("global_load_dwordx4 %0, %1, off sc0 sc1" : "=v"(r) : "v"(p) : "memory");
  return r;
}
DEV u32 ld_u32_coh(const u32* p) {            // includes waitcnt
  u32 r;
  asm volatile("global_load_dword %0, %1, off sc0 sc1\n\ts_waitcnt vmcnt(0)"
               : "=v"(r) : "v"(p) : "memory");
  return r;
}
DEV void st_u16_coh(u16* p, u16 v) {
  u32 d = v;
  asm volatile("global_store_short %0, %1, off sc0 sc1" :: "v"(p), "v"(d) : "memory");
}
DEV void st_u32_coh(u32* p, u32 v) {
  asm volatile("global_store_dword %0, %1, off sc0 sc1" :: "v"(p), "v"(v) : "memory");
}
DEV void vm_drain() { asm volatile("s_waitcnt vmcnt(0)" ::: "memory"); }

// ---------------- ws layout (bytes) ----------------
constexpr size_t OFF_CNT  = 0;                       // 2048 B: [0]=phase ctr, tags at +64 u32
constexpr size_t OFF_WT0F = 2048;
constexpr size_t NE_WT0   = 512 * 1024;              // W^T [512][1024] per plane
constexpr size_t SZ_WT0   = NE_WT0 * 2 * 2;          // hi+lo
constexpr size_t OFF_WT0B = OFF_WT0F + SZ_WT0;
constexpr size_t OFF_WT1F = OFF_WT0B + SZ_WT0;
constexpr size_t NE_WT1   = 512 * 1536;              // W^T [512][1536]
constexpr size_t SZ_WT1   = NE_WT1 * 2 * 2;
constexpr size_t OFF_WT1B = OFF_WT1F + SZ_WT1;
constexpr size_t OFF_XWF  = OFF_WT1B + SZ_WT1;       // f32 [512][32][512]
constexpr size_t SZ_XW    = 16384ull * 512 * 4;
constexpr size_t OFF_XWB  = OFF_XWF + SZ_XW;
constexpr size_t OFF_Y0   = OFF_XWB + SZ_XW;         // f32 [512][32][1024]
constexpr size_t SZ_Y0    = 16384ull * 1024 * 4;
constexpr size_t OFF_H    = OFF_Y0 + SZ_Y0;          // 4 dl x (hi b0,b1 | lo b0,b1) x 16384 u16

// Phase barrier: ONE release RMW + relaxed polling + ONE acquire fence per WG.
DEV void phase_barrier(u32* c, u32 target) {
  __syncthreads();
  if (threadIdx.x == 0) {
    __hip_atomic_fetch_add(c, 1u, __ATOMIC_RELEASE, __HIP_MEMORY_SCOPE_AGENT);
    while (__hip_atomic_load(c, __ATOMIC_RELAXED, __HIP_MEMORY_SCOPE_AGENT) < target)
      __builtin_amdgcn_s_sleep(16);
    __builtin_amdgcn_fence(__ATOMIC_ACQUIRE, "agent");
  }
  __syncthreads();
}

// ---------------- projection GEMM: C[16384][512] = A[16384][K] @ W + bias ----------------
DEV void proj_phase(const float* __restrict__ A, bool perm, int bpitch, int bkoff, int K,
                    const u16* __restrict__ wfh, const u16* __restrict__ wfl,
                    const u16* __restrict__ wbh, const u16* __restrict__ wbl,
                    const float* __restrict__ biasF, const float* __restrict__ biasB,
                    float* __restrict__ Cf, float* __restrict__ Cb,
                    u16* aHi, u16* aLo, u16* bHi, u16* bLo) {
  const int tid = threadIdx.x;
  const int l = tid & 63, w = tid >> 6;
  const int lr = l & 15, lk = (l >> 4) * 8;
  const int wm = (w >> 1) * 64, wn = (w & 1) * 64;
  for (int t = blockIdx.x; t < 1024; t += 256) {
    const int dir = t >> 9, tile = t & 511;
    const int mbase = (tile >> 2) * 128, nbase = (tile & 3) * 128;
    const u16* bh_src = dir ? wbh : wfh;
    const u16* bl_src = dir ? wbl : wfl;
    const float* bias = dir ? biasB : biasF;
    float* C = dir ? Cb : Cf;
    f32x4 acc[4][4] = {};
    for (int kk = 0; kk < K; kk += 32) {
      {  // stage A (f32 -> hi/lo bf16) and B (pre-split) into LDS, [128][40] padded
        const int row = tid >> 1, half = tid & 1;
        const int r = mbase + row;
        const int srcRow = perm ? (((r & 31) << 9) + (r >> 5)) : r;
        const float* ap = A + (size_t)srcRow * K + kk + half * 16;
        f32x4 q0 = *(const f32x4*)(ap + 0);
        f32x4 q1 = *(const f32x4*)(ap + 4);
        f32x4 q2 = *(const f32x4*)(ap + 8);
        f32x4 q3 = *(const f32x4*)(ap + 12);
        short8 h0, l0, h1, l1;
        #pragma unroll
        for (int e = 0; e < 4; ++e) {
          { float v = q0[e]; u16 hv = f2bf(v); h0[e]   = (short)hv; l0[e]   = (short)f2bf(v - bf2f(hv)); }
          { float v = q1[e]; u16 hv = f2bf(v); h0[e+4] = (short)hv; l0[e+4] = (short)f2bf(v - bf2f(hv)); }
          { float v = q2[e]; u16 hv = f2bf(v); h1[e]   = (short)hv; l1[e]   = (short)f2bf(v - bf2f(hv)); }
          { float v = q3[e]; u16 hv = f2bf(v); h1[e+4] = (short)hv; l1[e+4] = (short)f2bf(v - bf2f(hv)); }
        }
        const int o = row * 40 + half * 16;
        *(short8*)&aHi[o] = h0; *(short8*)&aHi[o + 8] = h1;
        *(short8*)&aLo[o] = l0; *(short8*)&aLo[o + 8] = l1;
        const size_t bo = (size_t)(nbase + row) * bpitch + bkoff + kk + half * 16;
        *(short8*)&bHi[o]     = *(const short8*)&bh_src[bo];
        *(short8*)&bHi[o + 8] = *(const short8*)&bh_src[bo + 8];
        *(short8*)&bLo[o]     = *(const short8*)&bl_src[bo];
        *(short8*)&bLo[o + 8] = *(const short8*)&bl_src[bo + 8];
      }
      __syncthreads();
      short8 afh[4], afl[4], bfh[4], bfl[4];
      #pragma unroll
      for (int i = 0; i < 4; ++i) {
        afh[i] = *(short8*)&aHi[(wm + i * 16 + lr) * 40 + lk];
        afl[i] = *(short8*)&aLo[(wm + i * 16 + lr) * 40 + lk];
        bfh[i] = *(short8*)&bHi[(wn + i * 16 + lr) * 40 + lk];
        bfl[i] = *(short8*)&bLo[(wn + i * 16 + lr) * 40 + lk];
      }
      #pragma unroll
      for (int i = 0; i < 4; ++i)
        #pragma unroll
        for (int j = 0; j < 4; ++j) {
          acc[i][j] = MFMA(afh[i], bfh[j], acc[i][j]);
          acc[i][j] = MFMA(afh[i], bfl[j], acc[i][j]);
          acc[i][j] = MFMA(afl[i], bfh[j], acc[i][j]);
        }
      __syncthreads();
    }
    #pragma unroll
    for (int i = 0; i < 4; ++i)
      #pragma unroll
      for (int j = 0; j < 4; ++j) {
        const int gcol = nbase + wn + j * 16 + lr;
        const float bv = bias[gcol];
        #pragma unroll
        for (int rr = 0; rr < 4; ++rr) {
          const int grow = mbase + wm + i * 16 + (l >> 4) * 4 + rr;
          C[(size_t)grow * 512 + gcol] = acc[i][j][rr] + bv;
        }
      }
  }
}

// ---------------- recurrence: 512 steps of h = tanh(xw[s] + h @ Wh) ----------------
// 16 WGs per direction; WG `slot` owns cols [slot*32, slot*32+32).
// Sync: per-wave tags (64/group) at the coherence point; h via sc0sc1 accesses.
DEV void recurrence(bool fwd, const float* __restrict__ xw,
                    const u16* __restrict__ wtHi, const u16* __restrict__ wtLo,
                    int wpitch, int wkoff,
                    u16* __restrict__ hHi, u16* __restrict__ hLo,
                    float* __restrict__ y0, int ycol0,
                    u32* tags, int slot, float* red) {
  const int l = threadIdx.x & 63, w = threadIdx.x >> 6;
  const int lr = l & 15, lk4 = l >> 4;
  const int j0 = slot * 32;
  short8 bh[2][4], bl[2][4];
  #pragma unroll
  for (int nt = 0; nt < 2; ++nt)
    #pragma unroll
    for (int ks = 0; ks < 4; ++ks) {
      const int col = j0 + nt * 16 + lr;
      const int k = w * 128 + ks * 32 + lk4 * 8;
      bh[nt][ks] = *(const short8*)&wtHi[(size_t)col * wpitch + wkoff + k];
      bl[nt][ks] = *(const short8*)&wtLo[(size_t)col * wpitch + wkoff + k];
    }
  const int mrow = (w >> 1) * 16 + lk4 * 4;
  const int ncol = j0 + (w & 1) * 16 + lr;
  const int myTag = slot * 4 + w;
  for (int t = 0; t < 512; ++t) {
    const int s = fwd ? t : (511 - t);
    // xw loads for this step (independent of h) — issue before the poll
    float xv[4];
    #pragma unroll
    for (int rr = 0; rr < 4; ++rr)
      xv[rr] = xw[(size_t)(s * 32 + mrow + rr) * 512 + ncol];
    // wait for all 64 waves of the group to have finished step t-1
    if (t) {
      for (;;) {
        u32 v = ld_u32_coh(tags + l);
        if (__all((int)(v >= (u32)t))) break;
        __builtin_amdgcn_s_sleep(1);
      }
    }
    const u16* hh = hHi + (t & 1) * 16384;
    const u16* hl = hLo + (t & 1) * 16384;
    u16* nhh = hHi + ((t & 1) ^ 1) * 16384;
    u16* nhl = hLo + ((t & 1) ^ 1) * 16384;
    // issue all h loads (coherence point), then one drain
    short8 a0h[4], a1h[4], a0l[4], a1l[4];
    #pragma unroll
    for (int ks = 0; ks < 4; ++ks) {
      const int k = w * 128 + ks * 32 + lk4 * 8;
      a0h[ks] = ld_b128_coh(&hh[lr * 512 + k]);
      a1h[ks] = ld_b128_coh(&hh[(16 + lr) * 512 + k]);
      a0l[ks] = ld_b128_coh(&hl[lr * 512 + k]);
      a1l[ks] = ld_b128_coh(&hl[(16 + lr) * 512 + k]);
    }
    vm_drain();
    __builtin_amdgcn_sched_barrier(0);
    f32x4 acc[2][2] = {};
    #pragma unroll
    for (int ks = 0; ks < 4; ++ks) {
      #pragma unroll
      for (int nt = 0; nt < 2; ++nt) {
        acc[0][nt] = MFMA(a0h[ks], bh[nt][ks], acc[0][nt]);
        acc[0][nt] = MFMA(a0h[ks], bl[nt][ks], acc[0][nt]);
        acc[0][nt] = MFMA(a0l[ks], bh[nt][ks], acc[0][nt]);
        acc[1][nt] = MFMA(a1h[ks], bh[nt][ks], acc[1][nt]);
        acc[1][nt] = MFMA(a1h[ks], bl[nt][ks], acc[1][nt]);
        acc[1][nt] = MFMA(a1l[ks], bh[nt][ks], acc[1][nt]);
      }
    }
    // cross-wave K reduction through LDS
    #pragma unroll
    for (int t4 = 0; t4 < 4; ++t4)
      *(f32x4*)&red[((w * 4 + t4) * 64 + l) * 4] = acc[t4 >> 1][t4 & 1];
    __syncthreads();
    f32x4 fin = *(const f32x4*)&red[((0 * 4 + w) * 64 + l) * 4];
    #pragma unroll
    for (int pw = 1; pw < 4; ++pw)
      fin += *(const f32x4*)&red[((pw * 4 + w) * 64 + l) * 4];
    #pragma unroll
    for (int rr = 0; rr < 4; ++rr) {
      const int row = mrow + rr;
      const float pre = xv[rr] + fin[rr];
      const float v = tanhf(pre);
      const u16 hv = f2bf(v);
      const u16 lv = f2bf(v - bf2f(hv));
      st_u16_coh(&nhh[row * 512 + ncol], hv);
      st_u16_coh(&nhl[row * 512 + ncol], lv);
      if (y0) y0[(size_t)(s * 32 + row) * 1024 + ycol0 + ncol] = v;
    }
    vm_drain();                       // h stores at coherence point
    if (l == 0) st_u32_coh(tags + myTag, (u32)(t + 1));
  }
}

__global__ void rnn_init(u32* c) { c[threadIdx.x] = 0; }

__global__ __launch_bounds__(256, 1) void rnn_main(
    const float* __restrict__ x,
    const float* __restrict__ Wf0, const float* __restrict__ bf0,
    const float* __restrict__ Wb0, const float* __restrict__ bb0,
    const float* __restrict__ Wf1, const float* __restrict__ bf1,
    const float* __restrict__ Wb1, const float* __restrict__ bb1,
    const float* __restrict__ Wfc, const float* __restrict__ bfc,
    float* __restrict__ out, char* __restrict__ ws) {
  __shared__ __align__(16) u16 lds[20480];          // 40 KB
  u16* aHi = lds; u16* aLo = lds + 5120; u16* bHi = lds + 10240; u16* bLo = lds + 15360;
  float* red = (float*)lds;

  u32* cnt = (u32*)(ws + OFF_CNT);
  u16* wt0f_hi = (u16*)(ws + OFF_WT0F); u16* wt0f_lo = wt0f_hi + NE_WT0;
  u16* wt0b_hi = (u16*)(ws + OFF_WT0B); u16* wt0b_lo = wt0b_hi + NE_WT0;
  u16* wt1f_hi = (u16*)(ws + OFF_WT1F); u16* wt1f_lo = wt1f_hi + NE_WT1;
  u16* wt1b_hi = (u16*)(ws + OFF_WT1B); u16* wt1b_lo = wt1b_hi + NE_WT1;
  float* xwf = (float*)(ws + OFF_XWF);
  float* xwb = (float*)(ws + OFF_XWB);
  float* y0  = (float*)(ws + OFF_Y0);
  u16* hb = (u16*)(ws + OFF_H);

  const int gtid = blockIdx.x * 256 + threadIdx.x;

  // ---- init: split+transpose weights, zero h state ----
  for (u32 j = gtid; j < (u32)NE_WT0; j += 65536u) {
    const u32 n = j >> 10, r = j & 1023;
    float v = Wf0[(size_t)r * 512 + n];
    u16 hv = f2bf(v); wt0f_hi[j] = hv; wt0f_lo[j] = f2bf(v - bf2f(hv));
    v = Wb0[(size_t)r * 512 + n];
    hv = f2bf(v); wt0b_hi[j] = hv; wt0b_lo[j] = f2bf(v - bf2f(hv));
  }
  for (u32 j = gtid; j < (u32)NE_WT1; j += 65536u) {
    const u32 n = j / 1536u, r = j - n * 1536u;
    float v = Wf1[(size_t)r * 512 + n];
    u16 hv = f2bf(v); wt1f_hi[j] = hv; wt1f_lo[j] = f2bf(v - bf2f(hv));
    v = Wb1[(size_t)r * 512 + n];
    hv = f2bf(v); wt1b_hi[j] = hv; wt1b_lo[j] = f2bf(v - bf2f(hv));
  }
  for (u32 j = gtid; j < 131072u; j += 65536u) ((u32*)hb)[j] = 0;

  u32 ep = 0;
  phase_barrier(cnt, (++ep) * 256);

  // ---- layer-0 input projection ----
  proj_phase(x, true, 1024, 0, 512, wt0f_hi, wt0f_lo, wt0b_hi, wt0b_lo,
             bf0, bb0, xwf, xwb, aHi, aLo, bHi, bLo);
  phase_barrier(cnt, (++ep) * 256);

  const int bid = blockIdx.x;
  const bool rf = bid < 16;                 // fwd group: bids 0..15 (2 per XCD)
  const bool rb = bid >= 16 && bid < 32;    // bwd group: bids 16..31
  const int slot = bid & 15;

  // ---- layer-0 recurrence (fwd || bwd), writes y0 ----
  if (rf)      recurrence(true,  xwf, wt0f_hi, wt0f_lo, 1024, 512,
                          hb + 0 * 65536, hb + 0 * 65536 + 32768, y0, 0,   cnt + 64,  slot, red);
  else if (rb) recurrence(false, xwb, wt0b_hi, wt0b_lo, 1024, 512,
                          hb + 1 * 65536, hb + 1 * 65536 + 32768, y0, 512, cnt + 128, slot, red);
  phase_barrier(cnt, (++ep) * 256);

  // ---- layer-1 input projection (A = y0, K=1024) ----
  proj_phase(y0, false, 1536, 0, 1024, wt1f_hi, wt1f_lo, wt1b_hi, wt1b_lo,
             bf1, bb1, xwf, xwb, aHi, aLo, bHi, bLo);
  phase_barrier(cnt, (++ep) * 256);

  // ---- layer-1 recurrence ----
  if (rf)      recurrence(true,  xwf, wt1f_hi, wt1f_lo, 1536, 1024,
                          hb + 2 * 65536, hb + 2 * 65536 + 32768, nullptr, 0, cnt + 192, slot, red);
  else if (rb) recurrence(false, xwb, wt1b_hi, wt1b_lo, 1536, 1024,
                          hb + 3 * 65536, hb + 3 * 65536 + 32768, nullptr, 0, cnt + 256, slot, red);
  phase_barrier(cnt, (++ep) * 256);

  // ---- finals: hf0,hb0,hf1,hb1 -> d_out (state in buf0 after 512 steps) ----
  {
    const int i = gtid;                 // 65536 values exactly
    const int dl = i >> 14, idx = i & 16383;
    const u16* hh = hb + dl * 65536;
    const u16* hl = hh + 32768;
    const float v = bf2f(hh[idx]) + bf2f(hl[idx]);
    const int base = 8192 + ((dl & 1) ? 32768 : 0) + ((dl >> 1) ? 16384 : 0);
    out[base + idx] = v;
  }
  // ---- FC: logits = [hf1|hb1] @ Wfc + bfc ----
  if (bid < 32) {
    const int gid = gtid;
    const int b = gid >> 8, o = gid & 255;
    const u16* f1h = hb + 2 * 65536; const u16* f1l = f1h + 32768;
    const u16* b1h = hb + 3 * 65536; const u16* b1l = b1h + 32768;
    float a = bfc[o];
    for (int k = 0; k < 512; ++k)
      a += (bf2f(f1h[b * 512 + k]) + bf2f(f1l[b * 512 + k])) * Wfc[(size_t)k * 256 + o];
    for (int k = 0; k < 512; ++k)
      a += (bf2f(b1h[b * 512 + k]) + bf2f(b1l[b * 512 + k])) * Wfc[(size_t)(512 + k) * 256 + o];
    out[gid] = a;
  }
}

extern "C" void kernel_launch(void* const* d_in, const int* in_sizes, int n_in,
                              void* d_out, int out_size, void* d_ws, size_t ws_size,
                              hipStream_t stream) {
  (void)in_sizes; (void)n_in; (void)out_size; (void)ws_size;
  const float* x   = (const float*)d_in[0];
  const float* Wf0 = (const float*)d_in[1];
  const float* bf0 = (const float*)d_in[2];
  const float* Wb0 = (const float*)d_in[3];
  const float* bb0 = (const float*)d_in[4];
  const float* Wf1 = (const float*)d_in[5];
  const float* bf1 = (const float*)d_in[6];
  const float* Wb1 = (const float*)d_in[7];
  const float* bb1 = (const float*)d_in[8];
  const float* Wfc = (const float*)d_in[9];
  const float* bfc = (const float*)d_in[10];
  rnn_init<<<1, 512, 0, stream>>>((u32*)d_ws);
  rnn_main<<<256, 256, 0, stream>>>(x, Wf0, bf0, Wb0, bb0, Wf1, bf1, Wb1, bb1,
                                    Wfc, bfc, (float*)d_out, (char*)d_ws);
}

// Round 3
// 6243.421 us; speedup vs baseline: 2.3066x; 1.0153x over previous
//
#include <hip/hip_runtime.h>

// BidirectionalRNN on MI355X — round 3: swapped-operand MFMA recurrence,
// 8 WGs/direction, per-wave tags, manual vmcnt load/compute pipeline,
// packed 8B h stores, fast tanh. Proj/init/finals unchanged from round 2.

typedef unsigned short u16;
typedef unsigned int u32;
typedef __attribute__((ext_vector_type(8))) short short8;
typedef __attribute__((ext_vector_type(4))) float f32x4;
typedef __attribute__((ext_vector_type(2))) unsigned int u32x2;

#define DEV static __device__ __forceinline__

DEV u16 f2bf(float f) {                       // f32 -> bf16 RNE
  u32 u = __builtin_bit_cast(u32, f);
  u = (u + 0x7fffu + ((u >> 16) & 1u)) >> 16;
  return (u16)u;
}
DEV float bf2f(u16 h) { return __builtin_bit_cast(float, ((u32)h) << 16); }

DEV f32x4 MFMA(short8 a, short8 b, f32x4 c) {
  return __builtin_amdgcn_mfma_f32_16x16x32_bf16(a, b, c, 0, 0, 0);
}

DEV float fast_tanh(float x) {                // (e^2x-1)/(e^2x+1) via v_exp+v_rcp
  float e = exp2f(x * 2.885390082f);
  return 1.0f - 2.0f * __builtin_amdgcn_rcpf(e + 1.0f);
}

// ---- coherence-point (bypass L1/L2) access helpers ----
DEV short8 ld_b128_coh(const u16* p) {        // issue only; caller waits vmcnt
  short8 r;
  asm volatile("global_load_dwordx4 %0, %1, off sc0 sc1" : "=v"(r) : "v"(p) : "memory");
  return r;
}
DEV f32x4 ld_f32x4_vm(const float* p) {       // cached load, but vmcnt-counted in asm order
  f32x4 r;
  asm volatile("global_load_dwordx4 %0, %1, off" : "=v"(r) : "v"(p) : "memory");
  return r;
}
DEV u32 ld_u32_coh(const u32* p) {            // includes waitcnt
  u32 r;
  asm volatile("global_load_dword %0, %1, off sc0 sc1\n\ts_waitcnt vmcnt(0)"
               : "=v"(r) : "v"(p) : "memory");
  return r;
}
DEV void st_b64_coh(u16* p, u32x2 v) {
  asm volatile("global_store_dwordx2 %0, %1, off sc0 sc1" :: "v"(p), "v"(v) : "memory");
}
DEV void st_u32_coh(u32* p, u32 v) {
  asm volatile("global_store_dword %0, %1, off sc0 sc1" :: "v"(p), "v"(v) : "memory");
}
DEV void vm_drain() { asm volatile("s_waitcnt vmcnt(0)" ::: "memory"); }

// ---------------- ws layout (bytes) ----------------
constexpr size_t OFF_CNT  = 0;                       // 2048 B: [0]=phase ctr; tags at +64..
constexpr size_t OFF_WT0F = 2048;
constexpr size_t NE_WT0   = 512 * 1024;              // W^T [512][1024] per plane
constexpr size_t SZ_WT0   = NE_WT0 * 2 * 2;          // hi+lo
constexpr size_t OFF_WT0B = OFF_WT0F + SZ_WT0;
constexpr size_t OFF_WT1F = OFF_WT0B + SZ_WT0;
constexpr size_t NE_WT1   = 512 * 1536;              // W^T [512][1536]
constexpr size_t SZ_WT1   = NE_WT1 * 2 * 2;
constexpr size_t OFF_WT1B = OFF_WT1F + SZ_WT1;
constexpr size_t OFF_XWF  = OFF_WT1B + SZ_WT1;       // f32 [512][32][512]
constexpr size_t SZ_XW    = 16384ull * 512 * 4;
constexpr size_t OFF_XWB  = OFF_XWF + SZ_XW;
constexpr size_t OFF_Y0   = OFF_XWB + SZ_XW;         // f32 [512][32][1024]
constexpr size_t SZ_Y0    = 16384ull * 1024 * 4;
constexpr size_t OFF_H    = OFF_Y0 + SZ_Y0;          // 4 dl x (hi b0,b1 | lo b0,b1) x 16384 u16

// Phase barrier: ONE release RMW + relaxed polling + ONE acquire fence per WG.
DEV void phase_barrier(u32* c, u32 target) {
  __syncthreads();
  if (threadIdx.x == 0) {
    __hip_atomic_fetch_add(c, 1u, __ATOMIC_RELEASE, __HIP_MEMORY_SCOPE_AGENT);
    while (__hip_atomic_load(c, __ATOMIC_RELAXED, __HIP_MEMORY_SCOPE_AGENT) < target)
      __builtin_amdgcn_s_sleep(16);
    __builtin_amdgcn_fence(__ATOMIC_ACQUIRE, "agent");
  }
  __syncthreads();
}

// ---------------- projection GEMM: C[16384][512] = A[16384][K] @ W + bias ----------------
DEV void proj_phase(const float* __restrict__ A, bool perm, int bpitch, int bkoff, int K,
                    const u16* __restrict__ wfh, const u16* __restrict__ wfl,
                    const u16* __restrict__ wbh, const u16* __restrict__ wbl,
                    const float* __restrict__ biasF, const float* __restrict__ biasB,
                    float* __restrict__ Cf, float* __restrict__ Cb,
                    u16* aHi, u16* aLo, u16* bHi, u16* bLo) {
  const int tid = threadIdx.x;
  const int l = tid & 63, w = tid >> 6;
  const int lr = l & 15, lk = (l >> 4) * 8;
  const int wm = (w >> 1) * 64, wn = (w & 1) * 64;
  for (int t = blockIdx.x; t < 1024; t += 256) {
    const int dir = t >> 9, tile = t & 511;
    const int mbase = (tile >> 2) * 128, nbase = (tile & 3) * 128;
    const u16* bh_src = dir ? wbh : wfh;
    const u16* bl_src = dir ? wbl : wfl;
    const float* bias = dir ? biasB : biasF;
    float* C = dir ? Cb : Cf;
    f32x4 acc[4][4] = {};
    for (int kk = 0; kk < K; kk += 32) {
      {  // stage A (f32 -> hi/lo bf16) and B (pre-split) into LDS, [128][40] padded
        const int row = tid >> 1, half = tid & 1;
        const int r = mbase + row;
        const int srcRow = perm ? (((r & 31) << 9) + (r >> 5)) : r;
        const float* ap = A + (size_t)srcRow * K + kk + half * 16;
        f32x4 q0 = *(const f32x4*)(ap + 0);
        f32x4 q1 = *(const f32x4*)(ap + 4);
        f32x4 q2 = *(const f32x4*)(ap + 8);
        f32x4 q3 = *(const f32x4*)(ap + 12);
        short8 h0, l0, h1, l1;
        #pragma unroll
        for (int e = 0; e < 4; ++e) {
          { float v = q0[e]; u16 hv = f2bf(v); h0[e]   = (short)hv; l0[e]   = (short)f2bf(v - bf2f(hv)); }
          { float v = q1[e]; u16 hv = f2bf(v); h0[e+4] = (short)hv; l0[e+4] = (short)f2bf(v - bf2f(hv)); }
          { float v = q2[e]; u16 hv = f2bf(v); h1[e]   = (short)hv; l1[e]   = (short)f2bf(v - bf2f(hv)); }
          { float v = q3[e]; u16 hv = f2bf(v); h1[e+4] = (short)hv; l1[e+4] = (short)f2bf(v - bf2f(hv)); }
        }
        const int o = row * 40 + half * 16;
        *(short8*)&aHi[o] = h0; *(short8*)&aHi[o + 8] = h1;
        *(short8*)&aLo[o] = l0; *(short8*)&aLo[o + 8] = l1;
        const size_t bo = (size_t)(nbase + row) * bpitch + bkoff + kk + half * 16;
        *(short8*)&bHi[o]     = *(const short8*)&bh_src[bo];
        *(short8*)&bHi[o + 8] = *(const short8*)&bh_src[bo + 8];
        *(short8*)&bLo[o]     = *(const short8*)&bl_src[bo];
        *(short8*)&bLo[o + 8] = *(const short8*)&bl_src[bo + 8];
      }
      __syncthreads();
      short8 afh[4], afl[4], bfh[4], bfl[4];
      #pragma unroll
      for (int i = 0; i < 4; ++i) {
        afh[i] = *(short8*)&aHi[(wm + i * 16 + lr) * 40 + lk];
        afl[i] = *(short8*)&aLo[(wm + i * 16 + lr) * 40 + lk];
        bfh[i] = *(short8*)&bHi[(wn + i * 16 + lr) * 40 + lk];
        bfl[i] = *(short8*)&bLo[(wn + i * 16 + lr) * 40 + lk];
      }
      #pragma unroll
      for (int i = 0; i < 4; ++i)
        #pragma unroll
        for (int j = 0; j < 4; ++j) {
          acc[i][j] = MFMA(afh[i], bfh[j], acc[i][j]);
          acc[i][j] = MFMA(afh[i], bfl[j], acc[i][j]);
          acc[i][j] = MFMA(afl[i], bfh[j], acc[i][j]);
        }
      __syncthreads();
    }
    #pragma unroll
    for (int i = 0; i < 4; ++i)
      #pragma unroll
      for (int j = 0; j < 4; ++j) {
        const int gcol = nbase + wn + j * 16 + lr;
        const float bv = bias[gcol];
        #pragma unroll
        for (int rr = 0; rr < 4; ++rr) {
          const int grow = mbase + wm + i * 16 + (l >> 4) * 4 + rr;
          C[(size_t)grow * 512 + gcol] = acc[i][j][rr] + bv;
        }
      }
  }
}

// ---------------- recurrence: 512 steps of h = tanh(xw[s] + h @ Wh) ----------------
// 8 WGs per direction; WG `wgslot` owns cols [wgslot*64, +64). Wave w K-chunk
// [w*128,+128); swapped-operand MFMA gives acc^T layout (lane = out-row, 4
// consecutive out-cols per reg) -> packed 8B stores + f32x4 xw loads.
// Per-wave tags; one __syncthreads/step (cross-wave K reduce through LDS).
DEV void recurrence(bool fwd, const float* __restrict__ xw,
                    const u16* __restrict__ wtHi, const u16* __restrict__ wtLo,
                    int wpitch, int wkoff,
                    u16* __restrict__ hHi, u16* __restrict__ hLo,
                    float* __restrict__ y0, int ycol0,
                    u32* tags, int wgslot, float* red) {
  const int tid = threadIdx.x;
  const int l = tid & 63, w = tid >> 6;
  const int lr = l & 15, lk4 = l >> 4;
  const int c0 = wgslot * 64;
  // A-operand: W^T fragments (lane: out-col = base+lr, k = lk4*8)
  short8 wfh[4][4], wfl[4][4];
  #pragma unroll
  for (int ct = 0; ct < 4; ++ct)
    #pragma unroll
    for (int ks = 0; ks < 4; ++ks) {
      const size_t o = (size_t)(c0 + ct * 16 + lr) * wpitch + wkoff + w * 128 + ks * 32 + lk4 * 8;
      wfh[ct][ks] = *(const short8*)&wtHi[o];
      wfl[ct][ks] = *(const short8*)&wtLo[o];
    }
  // finish role: tiles p1=w, p2=w+4 (p = ct*2+rT): same row, cols +32 apart
  const int frow = (w & 1) * 16 + lr;
  const int fcb  = c0 + (w >> 1) * 16 + lk4 * 4;
  const int myTag = wgslot * 4 + w;
  for (int t = 0; t < 512; ++t) {
    const int s = fwd ? t : (511 - t);
    // xw prefetch (independent of h) — issued before the poll, held in regs
    const float* xwp = xw + (size_t)(s * 32 + frow) * 512 + fcb;
    f32x4 xwA = ld_f32x4_vm(xwp);
    f32x4 xwB = ld_f32x4_vm(xwp + 32);
    if (t) {
      for (;;) {
        u32 v = ld_u32_coh(tags + (l & 31));
        if (__all((int)(v >= (u32)t))) break;
      }
    }
    const u16* hh = hHi + (t & 1) * 16384;
    const u16* hl = hLo + (t & 1) * 16384;
    u16* nhh = hHi + ((t & 1) ^ 1) * 16384;
    u16* nhl = hLo + ((t & 1) ^ 1) * 16384;
    // issue all 16 h loads (B-operand frags: lane = out-row lr / 16+lr)
    short8 hfh0[4], hfl0[4], hfh1[4], hfl1[4];
    #pragma unroll
    for (int g = 0; g < 4; ++g) {
      const int k = w * 128 + g * 32 + lk4 * 8;
      hfh0[g] = ld_b128_coh(&hh[lr * 512 + k]);
      hfl0[g] = ld_b128_coh(&hl[lr * 512 + k]);
      hfh1[g] = ld_b128_coh(&hh[(16 + lr) * 512 + k]);
      hfl1[g] = ld_b128_coh(&hl[(16 + lr) * 512 + k]);
    }
    f32x4 acc[4][2] = {};
    #pragma unroll
    for (int g = 0; g < 4; ++g) {
      if (g == 0)      asm volatile("s_waitcnt vmcnt(12)" ::: "memory");
      else if (g == 1) asm volatile("s_waitcnt vmcnt(8)"  ::: "memory");
      else if (g == 2) asm volatile("s_waitcnt vmcnt(4)"  ::: "memory");
      else             asm volatile("s_waitcnt vmcnt(0)"  ::: "memory");
      __builtin_amdgcn_sched_barrier(0);
      #pragma unroll
      for (int ct = 0; ct < 4; ++ct) {
        acc[ct][0] = MFMA(wfh[ct][g], hfh0[g], acc[ct][0]);
        acc[ct][0] = MFMA(wfh[ct][g], hfl0[g], acc[ct][0]);
        acc[ct][0] = MFMA(wfl[ct][g], hfh0[g], acc[ct][0]);
        acc[ct][1] = MFMA(wfh[ct][g], hfh1[g], acc[ct][1]);
        acc[ct][1] = MFMA(wfh[ct][g], hfl1[g], acc[ct][1]);
        acc[ct][1] = MFMA(wfl[ct][g], hfh1[g], acc[ct][1]);
      }
    }
    // cross-wave K reduce through LDS (contiguous 1KB slots, conflict-free)
    #pragma unroll
    for (int ct = 0; ct < 4; ++ct)
      #pragma unroll
      for (int rT = 0; rT < 2; ++rT)
        *(f32x4*)&red[((w * 8 + ct * 2 + rT) * 64 + l) * 4] = acc[ct][rT];
    __syncthreads();
    f32x4 finA = xwA, finB = xwB;
    #pragma unroll
    for (int wp = 0; wp < 4; ++wp) {
      finA += *(const f32x4*)&red[((wp * 8 + w) * 64 + l) * 4];
      finB += *(const f32x4*)&red[((wp * 8 + w + 4) * 64 + l) * 4];
    }
    f32x4 tA, tB;
    #pragma unroll
    for (int rr = 0; rr < 4; ++rr) { tA[rr] = fast_tanh(finA[rr]); tB[rr] = fast_tanh(finB[rr]); }
    u32x2 hwA, lwA, hwB, lwB;
    {
      u16 hv[8], lv[8];
      #pragma unroll
      for (int i = 0; i < 4; ++i) {
        hv[i] = f2bf(tA[i]); lv[i] = f2bf(tA[i] - bf2f(hv[i]));
        hv[4 + i] = f2bf(tB[i]); lv[4 + i] = f2bf(tB[i] - bf2f(hv[4 + i]));
      }
      hwA[0] = (u32)hv[0] | ((u32)hv[1] << 16); hwA[1] = (u32)hv[2] | ((u32)hv[3] << 16);
      lwA[0] = (u32)lv[0] | ((u32)lv[1] << 16); lwA[1] = (u32)lv[2] | ((u32)lv[3] << 16);
      hwB[0] = (u32)hv[4] | ((u32)hv[5] << 16); hwB[1] = (u32)hv[6] | ((u32)hv[7] << 16);
      lwB[0] = (u32)lv[4] | ((u32)lv[5] << 16); lwB[1] = (u32)lv[6] | ((u32)lv[7] << 16);
    }
    st_b64_coh(&nhh[frow * 512 + fcb], hwA);
    st_b64_coh(&nhl[frow * 512 + fcb], lwA);
    st_b64_coh(&nhh[frow * 512 + fcb + 32], hwB);
    st_b64_coh(&nhl[frow * 512 + fcb + 32], lwB);
    if (y0) {
      *(f32x4*)&y0[(size_t)(s * 32 + frow) * 1024 + ycol0 + fcb] = tA;
      *(f32x4*)&y0[(size_t)(s * 32 + frow) * 1024 + ycol0 + fcb + 32] = tB;
    }
    vm_drain();
    if (l == 0) st_u32_coh(tags + myTag, (u32)(t + 1));
  }
}

__global__ void rnn_init(u32* c) { c[threadIdx.x] = 0; }

__global__ __launch_bounds__(256, 1) void rnn_main(
    const float* __restrict__ x,
    const float* __restrict__ Wf0, const float* __restrict__ bf0,
    const float* __restrict__ Wb0, const float* __restrict__ bb0,
    const float* __restrict__ Wf1, const float* __restrict__ bf1,
    const float* __restrict__ Wb1, const float* __restrict__ bb1,
    const float* __restrict__ Wfc, const float* __restrict__ bfc,
    float* __restrict__ out, char* __restrict__ ws) {
  __shared__ __align__(16) u16 lds[20480];          // 40 KB: proj tiles / rec reduce
  u16* aHi = lds; u16* aLo = lds + 5120; u16* bHi = lds + 10240; u16* bLo = lds + 15360;
  float* red = (float*)lds;

  u32* cnt = (u32*)(ws + OFF_CNT);
  u16* wt0f_hi = (u16*)(ws + OFF_WT0F); u16* wt0f_lo = wt0f_hi + NE_WT0;
  u16* wt0b_hi = (u16*)(ws + OFF_WT0B); u16* wt0b_lo = wt0b_hi + NE_WT0;
  u16* wt1f_hi = (u16*)(ws + OFF_WT1F); u16* wt1f_lo = wt1f_hi + NE_WT1;
  u16* wt1b_hi = (u16*)(ws + OFF_WT1B); u16* wt1b_lo = wt1b_hi + NE_WT1;
  float* xwf = (float*)(ws + OFF_XWF);
  float* xwb = (float*)(ws + OFF_XWB);
  float* y0  = (float*)(ws + OFF_Y0);
  u16* hb = (u16*)(ws + OFF_H);

  const int gtid = blockIdx.x * 256 + threadIdx.x;

  // ---- init: split+transpose weights, zero h state ----
  for (u32 j = gtid; j < (u32)NE_WT0; j += 65536u) {
    const u32 n = j >> 10, r = j & 1023;
    float v = Wf0[(size_t)r * 512 + n];
    u16 hv = f2bf(v); wt0f_hi[j] = hv; wt0f_lo[j] = f2bf(v - bf2f(hv));
    v = Wb0[(size_t)r * 512 + n];
    hv = f2bf(v); wt0b_hi[j] = hv; wt0b_lo[j] = f2bf(v - bf2f(hv));
  }
  for (u32 j = gtid; j < (u32)NE_WT1; j += 65536u) {
    const u32 n = j / 1536u, r = j - n * 1536u;
    float v = Wf1[(size_t)r * 512 + n];
    u16 hv = f2bf(v); wt1f_hi[j] = hv; wt1f_lo[j] = f2bf(v - bf2f(hv));
    v = Wb1[(size_t)r * 512 + n];
    hv = f2bf(v); wt1b_hi[j] = hv; wt1b_lo[j] = f2bf(v - bf2f(hv));
  }
  for (u32 j = gtid; j < 131072u; j += 65536u) ((u32*)hb)[j] = 0;

  u32 ep = 0;
  phase_barrier(cnt, (++ep) * 256);

  // ---- layer-0 input projection ----
  proj_phase(x, true, 1024, 0, 512, wt0f_hi, wt0f_lo, wt0b_hi, wt0b_lo,
             bf0, bb0, xwf, xwb, aHi, aLo, bHi, bLo);
  phase_barrier(cnt, (++ep) * 256);

  const int bid = blockIdx.x;
  const bool rf = bid < 8;                   // fwd: 1 WG per XCD
  const bool rb = bid >= 8 && bid < 16;      // bwd: 1 WG per XCD
  const int slot = bid & 7;

  // ---- layer-0 recurrence (fwd || bwd), writes y0 ----
  if (rf)      recurrence(true,  xwf, wt0f_hi, wt0f_lo, 1024, 512,
                          hb + 0 * 65536, hb + 0 * 65536 + 32768, y0, 0,   cnt + 64,  slot, red);
  else if (rb) recurrence(false, xwb, wt0b_hi, wt0b_lo, 1024, 512,
                          hb + 1 * 65536, hb + 1 * 65536 + 32768, y0, 512, cnt + 96,  slot, red);
  phase_barrier(cnt, (++ep) * 256);

  // ---- layer-1 input projection (A = y0, K=1024) ----
  proj_phase(y0, false, 1536, 0, 1024, wt1f_hi, wt1f_lo, wt1b_hi, wt1b_lo,
             bf1, bb1, xwf, xwb, aHi, aLo, bHi, bLo);
  phase_barrier(cnt, (++ep) * 256);

  // ---- layer-1 recurrence ----
  if (rf)      recurrence(true,  xwf, wt1f_hi, wt1f_lo, 1536, 1024,
                          hb + 2 * 65536, hb + 2 * 65536 + 32768, nullptr, 0, cnt + 128, slot, red);
  else if (rb) recurrence(false, xwb, wt1b_hi, wt1b_lo, 1536, 1024,
                          hb + 3 * 65536, hb + 3 * 65536 + 32768, nullptr, 0, cnt + 160, slot, red);
  phase_barrier(cnt, (++ep) * 256);

  // ---- finals: hf0,hb0,hf1,hb1 -> d_out (state in buf0 after 512 steps) ----
  {
    const int i = gtid;                 // 65536 values exactly
    const int dl = i >> 14, idx = i & 16383;
    const u16* hh = hb + dl * 65536;
    const u16* hl = hh + 32768;
    const float v = bf2f(hh[idx]) + bf2f(hl[idx]);
    const int base = 8192 + ((dl & 1) ? 32768 : 0) + ((dl >> 1) ? 16384 : 0);
    out[base + idx] = v;
  }
  // ---- FC: logits = [hf1|hb1] @ Wfc + bfc ----
  if (bid < 32) {
    const int gid = gtid;
    const int b = gid >> 8, o = gid & 255;
    const u16* f1h = hb + 2 * 65536; const u16* f1l = f1h + 32768;
    const u16* b1h = hb + 3 * 65536; const u16* b1l = b1h + 32768;
    float a = bfc[o];
    for (int k = 0; k < 512; ++k)
      a += (bf2f(f1h[b * 512 + k]) + bf2f(f1l[b * 512 + k])) * Wfc[(size_t)k * 256 + o];
    for (int k = 0; k < 512; ++k)
      a += (bf2f(b1h[b * 512 + k]) + bf2f(b1l[b * 512 + k])) * Wfc[(size_t)(512 + k) * 256 + o];
    out[gid] = a;
  }
}

extern "C" void kernel_launch(void* const* d_in, const int* in_sizes, int n_in,
                              void* d_out, int out_size, void* d_ws, size_t ws_size,
                              hipStream_t stream) {
  (void)in_sizes; (void)n_in; (void)out_size; (void)ws_size;
  const float* x   = (const float*)d_in[0];
  const float* Wf0 = (const float*)d_in[1];
  const float* bf0 = (const float*)d_in[2];
  const float* Wb0 = (const float*)d_in[3];
  const float* bb0 = (const float*)d_in[4];
  const float* Wf1 = (const float*)d_in[5];
  const float* bf1 = (const float*)d_in[6];
  const float* Wb1 = (const float*)d_in[7];
  const float* bb1 = (const float*)d_in[8];
  const float* Wfc = (const float*)d_in[9];
  const float* bfc = (const float*)d_in[10];
  rnn_init<<<1, 512, 0, stream>>>((u32*)d_ws);
  rnn_main<<<256, 256, 0, stream>>>(x, Wf0, bf0, Wb0, bb0, Wf1, bf1, Wb1, bb1,
                                    Wfc, bfc, (float*)d_out, (char*)d_ws);
}

// Round 4
// 5498.493 us; speedup vs baseline: 2.6191x; 1.1355x over previous
//
#include <hip/hip_runtime.h>

// BidirectionalRNN on MI355X — round 4: kill L3 hot-line contention.
// Per-consumer mailbox sync (256B-strided lines), idle-WG poll backoff,
// y0 stores moved off the step critical path. Step body = round 3.

typedef unsigned short u16;
typedef unsigned int u32;
typedef __attribute__((ext_vector_type(8))) short short8;
typedef __attribute__((ext_vector_type(4))) float f32x4;
typedef __attribute__((ext_vector_type(2))) unsigned int u32x2;

#define DEV static __device__ __forceinline__

DEV u16 f2bf(float f) {                       // f32 -> bf16 RNE
  u32 u = __builtin_bit_cast(u32, f);
  u = (u + 0x7fffu + ((u >> 16) & 1u)) >> 16;
  return (u16)u;
}
DEV float bf2f(u16 h) { return __builtin_bit_cast(float, ((u32)h) << 16); }

DEV f32x4 MFMA(short8 a, short8 b, f32x4 c) {
  return __builtin_amdgcn_mfma_f32_16x16x32_bf16(a, b, c, 0, 0, 0);
}

DEV float fast_tanh(float x) {                // (e^2x-1)/(e^2x+1) via v_exp+v_rcp
  float e = exp2f(x * 2.885390082f);
  return 1.0f - 2.0f * __builtin_amdgcn_rcpf(e + 1.0f);
}

// ---- coherence-point (bypass L1/L2) access helpers ----
DEV short8 ld_b128_coh(const u16* p) {        // issue only; caller waits vmcnt
  short8 r;
  asm volatile("global_load_dwordx4 %0, %1, off sc0 sc1" : "=v"(r) : "v"(p) : "memory");
  return r;
}
DEV f32x4 ld_f32x4_vm(const float* p) {       // cached load, vmcnt-counted in asm order
  f32x4 r;
  asm volatile("global_load_dwordx4 %0, %1, off" : "=v"(r) : "v"(p) : "memory");
  return r;
}
DEV u32 ld_u32_coh(const u32* p) {            // includes waitcnt
  u32 r;
  asm volatile("global_load_dword %0, %1, off sc0 sc1\n\ts_waitcnt vmcnt(0)"
               : "=v"(r) : "v"(p) : "memory");
  return r;
}
DEV void st_b64_coh(u16* p, u32x2 v) {
  asm volatile("global_store_dwordx2 %0, %1, off sc0 sc1" :: "v"(p), "v"(v) : "memory");
}
DEV void st_u32_coh(u32* p, u32 v) {
  asm volatile("global_store_dword %0, %1, off sc0 sc1" :: "v"(p), "v"(v) : "memory");
}
DEV void vm_drain() { asm volatile("s_waitcnt vmcnt(0)" ::: "memory"); }

// ---------------- ws layout (bytes) ----------------
// [0,1024):     phase counter (own line)
// [1024,9216):  4 mailbox regions (phase x dir), each 8 consumer lines x 256B
// [16384,...):  weights / xw / y0 / h
constexpr size_t OFF_CNT  = 0;
constexpr size_t OFF_MB   = 1024;                    // u32 base; region r at +r*512 u32
constexpr size_t OFF_WT0F = 16384;
constexpr size_t NE_WT0   = 512 * 1024;              // W^T [512][1024] per plane
constexpr size_t SZ_WT0   = NE_WT0 * 2 * 2;          // hi+lo
constexpr size_t OFF_WT0B = OFF_WT0F + SZ_WT0;
constexpr size_t OFF_WT1F = OFF_WT0B + SZ_WT0;
constexpr size_t NE_WT1   = 512 * 1536;              // W^T [512][1536]
constexpr size_t SZ_WT1   = NE_WT1 * 2 * 2;
constexpr size_t OFF_WT1B = OFF_WT1F + SZ_WT1;
constexpr size_t OFF_XWF  = OFF_WT1B + SZ_WT1;       // f32 [512][32][512]
constexpr size_t SZ_XW    = 16384ull * 512 * 4;
constexpr size_t OFF_XWB  = OFF_XWF + SZ_XW;
constexpr size_t OFF_Y0   = OFF_XWB + SZ_XW;         // f32 [512][32][1024]
constexpr size_t SZ_Y0    = 16384ull * 1024 * 4;
constexpr size_t OFF_H    = OFF_Y0 + SZ_Y0;          // 4 dl x (hi b0,b1 | lo b0,b1) x 16384 u16

// Phase barrier: ONE release RMW + relaxed poll (fine then coarse backoff)
// + ONE acquire fence per WG.
DEV void phase_barrier(u32* c, u32 target) {
  __syncthreads();
  if (threadIdx.x == 0) {
    __hip_atomic_fetch_add(c, 1u, __ATOMIC_RELEASE, __HIP_MEMORY_SCOPE_AGENT);
    int spins = 0;
    while (__hip_atomic_load(c, __ATOMIC_RELAXED, __HIP_MEMORY_SCOPE_AGENT) < target) {
      if (++spins < 16) {
        __builtin_amdgcn_s_sleep(32);
      } else {
        __builtin_amdgcn_s_sleep(127);
        __builtin_amdgcn_s_sleep(127);
      }
    }
    __builtin_amdgcn_fence(__ATOMIC_ACQUIRE, "agent");
  }
  __syncthreads();
}

// ---------------- projection GEMM: C[16384][512] = A[16384][K] @ W + bias ----------------
DEV void proj_phase(const float* __restrict__ A, bool perm, int bpitch, int bkoff, int K,
                    const u16* __restrict__ wfh, const u16* __restrict__ wfl,
                    const u16* __restrict__ wbh, const u16* __restrict__ wbl,
                    const float* __restrict__ biasF, const float* __restrict__ biasB,
                    float* __restrict__ Cf, float* __restrict__ Cb,
                    u16* aHi, u16* aLo, u16* bHi, u16* bLo) {
  const int tid = threadIdx.x;
  const int l = tid & 63, w = tid >> 6;
  const int lr = l & 15, lk = (l >> 4) * 8;
  const int wm = (w >> 1) * 64, wn = (w & 1) * 64;
  for (int t = blockIdx.x; t < 1024; t += 256) {
    const int dir = t >> 9, tile = t & 511;
    const int mbase = (tile >> 2) * 128, nbase = (tile & 3) * 128;
    const u16* bh_src = dir ? wbh : wfh;
    const u16* bl_src = dir ? wbl : wfl;
    const float* bias = dir ? biasB : biasF;
    float* C = dir ? Cb : Cf;
    f32x4 acc[4][4] = {};
    for (int kk = 0; kk < K; kk += 32) {
      {  // stage A (f32 -> hi/lo bf16) and B (pre-split) into LDS, [128][40] padded
        const int row = tid >> 1, half = tid & 1;
        const int r = mbase + row;
        const int srcRow = perm ? (((r & 31) << 9) + (r >> 5)) : r;
        const float* ap = A + (size_t)srcRow * K + kk + half * 16;
        f32x4 q0 = *(const f32x4*)(ap + 0);
        f32x4 q1 = *(const f32x4*)(ap + 4);
        f32x4 q2 = *(const f32x4*)(ap + 8);
        f32x4 q3 = *(const f32x4*)(ap + 12);
        short8 h0, l0, h1, l1;
        #pragma unroll
        for (int e = 0; e < 4; ++e) {
          { float v = q0[e]; u16 hv = f2bf(v); h0[e]   = (short)hv; l0[e]   = (short)f2bf(v - bf2f(hv)); }
          { float v = q1[e]; u16 hv = f2bf(v); h0[e+4] = (short)hv; l0[e+4] = (short)f2bf(v - bf2f(hv)); }
          { float v = q2[e]; u16 hv = f2bf(v); h1[e]   = (short)hv; l1[e]   = (short)f2bf(v - bf2f(hv)); }
          { float v = q3[e]; u16 hv = f2bf(v); h1[e+4] = (short)hv; l1[e+4] = (short)f2bf(v - bf2f(hv)); }
        }
        const int o = row * 40 + half * 16;
        *(short8*)&aHi[o] = h0; *(short8*)&aHi[o + 8] = h1;
        *(short8*)&aLo[o] = l0; *(short8*)&aLo[o + 8] = l1;
        const size_t bo = (size_t)(nbase + row) * bpitch + bkoff + kk + half * 16;
        *(short8*)&bHi[o]     = *(const short8*)&bh_src[bo];
        *(short8*)&bHi[o + 8] = *(const short8*)&bh_src[bo + 8];
        *(short8*)&bLo[o]     = *(const short8*)&bl_src[bo];
        *(short8*)&bLo[o + 8] = *(const short8*)&bl_src[bo + 8];
      }
      __syncthreads();
      short8 afh[4], afl[4], bfh[4], bfl[4];
      #pragma unroll
      for (int i = 0; i < 4; ++i) {
        afh[i] = *(short8*)&aHi[(wm + i * 16 + lr) * 40 + lk];
        afl[i] = *(short8*)&aLo[(wm + i * 16 + lr) * 40 + lk];
        bfh[i] = *(short8*)&bHi[(wn + i * 16 + lr) * 40 + lk];
        bfl[i] = *(short8*)&bLo[(wn + i * 16 + lr) * 40 + lk];
      }
      #pragma unroll
      for (int i = 0; i < 4; ++i)
        #pragma unroll
        for (int j = 0; j < 4; ++j) {
          acc[i][j] = MFMA(afh[i], bfh[j], acc[i][j]);
          acc[i][j] = MFMA(afh[i], bfl[j], acc[i][j]);
          acc[i][j] = MFMA(afl[i], bfh[j], acc[i][j]);
        }
      __syncthreads();
    }
    #pragma unroll
    for (int i = 0; i < 4; ++i)
      #pragma unroll
      for (int j = 0; j < 4; ++j) {
        const int gcol = nbase + wn + j * 16 + lr;
        const float bv = bias[gcol];
        #pragma unroll
        for (int rr = 0; rr < 4; ++rr) {
          const int grow = mbase + wm + i * 16 + (l >> 4) * 4 + rr;
          C[(size_t)grow * 512 + gcol] = acc[i][j][rr] + bv;
        }
      }
  }
}

// ---------------- recurrence: 512 steps of h = tanh(xw[s] + h @ Wh) ----------------
// 8 WGs per direction; WG `wgslot` owns cols [wgslot*64, +64). Wave w K-chunk
// [w*128,+128); swapped-operand MFMA (acc^T: lane = out-row, 4 consecutive
// out-cols per reg) -> packed 8B stores, f32x4 xw loads.
// Sync: per-consumer mailboxes. mb[c*64 + p*4 + w] (u32, 256B line stride):
// producer wave (p,w) posts t+1 into its slot of every consumer line c;
// consumer WG c polls only its own line.
DEV void recurrence(bool fwd, const float* __restrict__ xw,
                    const u16* __restrict__ wtHi, const u16* __restrict__ wtLo,
                    int wpitch, int wkoff,
                    u16* __restrict__ hHi, u16* __restrict__ hLo,
                    float* __restrict__ y0, int ycol0,
                    u32* mb, int wgslot, float* red) {
  const int tid = threadIdx.x;
  const int l = tid & 63, w = tid >> 6;
  const int lr = l & 15, lk4 = l >> 4;
  const int c0 = wgslot * 64;
  // A-operand: W^T fragments (lane: out-col = base+lr, k = lk4*8)
  short8 wfh[4][4], wfl[4][4];
  #pragma unroll
  for (int ct = 0; ct < 4; ++ct)
    #pragma unroll
    for (int ks = 0; ks < 4; ++ks) {
      const size_t o = (size_t)(c0 + ct * 16 + lr) * wpitch + wkoff + w * 128 + ks * 32 + lk4 * 8;
      wfh[ct][ks] = *(const short8*)&wtHi[o];
      wfl[ct][ks] = *(const short8*)&wtLo[o];
    }
  const int frow = (w & 1) * 16 + lr;
  const int fcb  = c0 + (w >> 1) * 16 + lk4 * 4;
  const u32 mySlot = (u32)(wgslot * 4 + w);
  u32* pollp = mb + wgslot * 64 + (l & 31);
  for (int t = 0; t < 512; ++t) {
    const int s = fwd ? t : (511 - t);
    // xw prefetch (independent of h) — issued before the poll, held in regs
    const float* xwp = xw + (size_t)(s * 32 + frow) * 512 + fcb;
    f32x4 xwA = ld_f32x4_vm(xwp);
    f32x4 xwB = ld_f32x4_vm(xwp + 32);
    if (t) {
      for (;;) {
        u32 v = ld_u32_coh(pollp);
        if (__all((int)(v >= (u32)t))) break;
      }
    }
    const u16* hh = hHi + (t & 1) * 16384;
    const u16* hl = hLo + (t & 1) * 16384;
    u16* nhh = hHi + ((t & 1) ^ 1) * 16384;
    u16* nhl = hLo + ((t & 1) ^ 1) * 16384;
    // issue all 16 h loads (B-operand frags: lane = out-row lr / 16+lr)
    short8 hfh0[4], hfl0[4], hfh1[4], hfl1[4];
    #pragma unroll
    for (int g = 0; g < 4; ++g) {
      const int k = w * 128 + g * 32 + lk4 * 8;
      hfh0[g] = ld_b128_coh(&hh[lr * 512 + k]);
      hfl0[g] = ld_b128_coh(&hl[lr * 512 + k]);
      hfh1[g] = ld_b128_coh(&hh[(16 + lr) * 512 + k]);
      hfl1[g] = ld_b128_coh(&hl[(16 + lr) * 512 + k]);
    }
    f32x4 acc[4][2] = {};
    #pragma unroll
    for (int g = 0; g < 4; ++g) {
      if (g == 0)      asm volatile("s_waitcnt vmcnt(12)" ::: "memory");
      else if (g == 1) asm volatile("s_waitcnt vmcnt(8)"  ::: "memory");
      else if (g == 2) asm volatile("s_waitcnt vmcnt(4)"  ::: "memory");
      else             asm volatile("s_waitcnt vmcnt(0)"  ::: "memory");
      __builtin_amdgcn_sched_barrier(0);
      #pragma unroll
      for (int ct = 0; ct < 4; ++ct) {
        acc[ct][0] = MFMA(wfh[ct][g], hfh0[g], acc[ct][0]);
        acc[ct][0] = MFMA(wfh[ct][g], hfl0[g], acc[ct][0]);
        acc[ct][0] = MFMA(wfl[ct][g], hfh0[g], acc[ct][0]);
        acc[ct][1] = MFMA(wfh[ct][g], hfh1[g], acc[ct][1]);
        acc[ct][1] = MFMA(wfh[ct][g], hfl1[g], acc[ct][1]);
        acc[ct][1] = MFMA(wfl[ct][g], hfh1[g], acc[ct][1]);
      }
    }
    // cross-wave K reduce through LDS (contiguous 1KB slots, conflict-free)
    #pragma unroll
    for (int ct = 0; ct < 4; ++ct)
      #pragma unroll
      for (int rT = 0; rT < 2; ++rT)
        *(f32x4*)&red[((w * 8 + ct * 2 + rT) * 64 + l) * 4] = acc[ct][rT];
    __syncthreads();
    f32x4 finA = xwA, finB = xwB;
    #pragma unroll
    for (int wp = 0; wp < 4; ++wp) {
      finA += *(const f32x4*)&red[((wp * 8 + w) * 64 + l) * 4];
      finB += *(const f32x4*)&red[((wp * 8 + w + 4) * 64 + l) * 4];
    }
    f32x4 tA, tB;
    #pragma unroll
    for (int rr = 0; rr < 4; ++rr) { tA[rr] = fast_tanh(finA[rr]); tB[rr] = fast_tanh(finB[rr]); }
    u32x2 hwA, lwA, hwB, lwB;
    {
      u16 hv[8], lv[8];
      #pragma unroll
      for (int i = 0; i < 4; ++i) {
        hv[i] = f2bf(tA[i]); lv[i] = f2bf(tA[i] - bf2f(hv[i]));
        hv[4 + i] = f2bf(tB[i]); lv[4 + i] = f2bf(tB[i] - bf2f(hv[4 + i]));
      }
      hwA[0] = (u32)hv[0] | ((u32)hv[1] << 16); hwA[1] = (u32)hv[2] | ((u32)hv[3] << 16);
      lwA[0] = (u32)lv[0] | ((u32)lv[1] << 16); lwA[1] = (u32)lv[2] | ((u32)lv[3] << 16);
      hwB[0] = (u32)hv[4] | ((u32)hv[5] << 16); hwB[1] = (u32)hv[6] | ((u32)hv[7] << 16);
      lwB[0] = (u32)lv[4] | ((u32)lv[5] << 16); lwB[1] = (u32)lv[6] | ((u32)lv[7] << 16);
    }
    st_b64_coh(&nhh[frow * 512 + fcb], hwA);
    st_b64_coh(&nhl[frow * 512 + fcb], lwA);
    st_b64_coh(&nhh[frow * 512 + fcb + 32], hwB);
    st_b64_coh(&nhl[frow * 512 + fcb + 32], lwB);
    vm_drain();                        // h committed at coherence point
    if (l < 8) st_u32_coh(mb + l * 64 + mySlot, (u32)(t + 1));   // post to 8 consumers
    if (y0) {                          // off the critical path; flushed at phase barrier
      *(f32x4*)&y0[(size_t)(s * 32 + frow) * 1024 + ycol0 + fcb] = tA;
      *(f32x4*)&y0[(size_t)(s * 32 + frow) * 1024 + ycol0 + fcb + 32] = tB;
    }
  }
}

__global__ void rnn_init(u32* c) {            // zero counters + mailboxes (16KB)
  #pragma unroll
  for (int i = 0; i < 16; ++i) c[threadIdx.x * 16 + i] = 0;
}

__global__ __launch_bounds__(256, 1) void rnn_main(
    const float* __restrict__ x,
    const float* __restrict__ Wf0, const float* __restrict__ bf0,
    const float* __restrict__ Wb0, const float* __restrict__ bb0,
    const float* __restrict__ Wf1, const float* __restrict__ bf1,
    const float* __restrict__ Wb1, const float* __restrict__ bb1,
    const float* __restrict__ Wfc, const float* __restrict__ bfc,
    float* __restrict__ out, char* __restrict__ ws) {
  __shared__ __align__(16) u16 lds[20480];          // 40 KB: proj tiles / rec reduce
  u16* aHi = lds; u16* aLo = lds + 5120; u16* bHi = lds + 10240; u16* bLo = lds + 15360;
  float* red = (float*)lds;

  u32* cnt = (u32*)(ws + OFF_CNT);
  u32* mbase = (u32*)(ws + OFF_MB);
  u16* wt0f_hi = (u16*)(ws + OFF_WT0F); u16* wt0f_lo = wt0f_hi + NE_WT0;
  u16* wt0b_hi = (u16*)(ws + OFF_WT0B); u16* wt0b_lo = wt0b_hi + NE_WT0;
  u16* wt1f_hi = (u16*)(ws + OFF_WT1F); u16* wt1f_lo = wt1f_hi + NE_WT1;
  u16* wt1b_hi = (u16*)(ws + OFF_WT1B); u16* wt1b_lo = wt1b_hi + NE_WT1;
  float* xwf = (float*)(ws + OFF_XWF);
  float* xwb = (float*)(ws + OFF_XWB);
  float* y0  = (float*)(ws + OFF_Y0);
  u16* hb = (u16*)(ws + OFF_H);

  const int gtid = blockIdx.x * 256 + threadIdx.x;

  // ---- init: split+transpose weights, zero h state ----
  for (u32 j = gtid; j < (u32)NE_WT0; j += 65536u) {
    const u32 n = j >> 10, r = j & 1023;
    float v = Wf0[(size_t)r * 512 + n];
    u16 hv = f2bf(v); wt0f_hi[j] = hv; wt0f_lo[j] = f2bf(v - bf2f(hv));
    v = Wb0[(size_t)r * 512 + n];
    hv = f2bf(v); wt0b_hi[j] = hv; wt0b_lo[j] = f2bf(v - bf2f(hv));
  }
  for (u32 j = gtid; j < (u32)NE_WT1; j += 65536u) {
    const u32 n = j / 1536u, r = j - n * 1536u;
    float v = Wf1[(size_t)r * 512 + n];
    u16 hv = f2bf(v); wt1f_hi[j] = hv; wt1f_lo[j] = f2bf(v - bf2f(hv));
    v = Wb1[(size_t)r * 512 + n];
    hv = f2bf(v); wt1b_hi[j] = hv; wt1b_lo[j] = f2bf(v - bf2f(hv));
  }
  for (u32 j = gtid; j < 131072u; j += 65536u) ((u32*)hb)[j] = 0;

  u32 ep = 0;
  phase_barrier(cnt, (++ep) * 256);

  // ---- layer-0 input projection ----
  proj_phase(x, true, 1024, 0, 512, wt0f_hi, wt0f_lo, wt0b_hi, wt0b_lo,
             bf0, bb0, xwf, xwb, aHi, aLo, bHi, bLo);
  phase_barrier(cnt, (++ep) * 256);

  const int bid = blockIdx.x;
  const bool rf = bid < 8;                   // fwd: 1 WG per XCD
  const bool rb = bid >= 8 && bid < 16;      // bwd: 1 WG per XCD
  const int slot = bid & 7;

  // ---- layer-0 recurrence (fwd || bwd), writes y0 ----
  if (rf)      recurrence(true,  xwf, wt0f_hi, wt0f_lo, 1024, 512,
                          hb + 0 * 65536, hb + 0 * 65536 + 32768, y0, 0,   mbase,        slot, red);
  else if (rb) recurrence(false, xwb, wt0b_hi, wt0b_lo, 1024, 512,
                          hb + 1 * 65536, hb + 1 * 65536 + 32768, y0, 512, mbase + 512,  slot, red);
  phase_barrier(cnt, (++ep) * 256);

  // ---- layer-1 input projection (A = y0, K=1024) ----
  proj_phase(y0, false, 1536, 0, 1024, wt1f_hi, wt1f_lo, wt1b_hi, wt1b_lo,
             bf1, bb1, xwf, xwb, aHi, aLo, bHi, bLo);
  phase_barrier(cnt, (++ep) * 256);

  // ---- layer-1 recurrence ----
  if (rf)      recurrence(true,  xwf, wt1f_hi, wt1f_lo, 1536, 1024,
                          hb + 2 * 65536, hb + 2 * 65536 + 32768, nullptr, 0, mbase + 1024, slot, red);
  else if (rb) recurrence(false, xwb, wt1b_hi, wt1b_lo, 1536, 1024,
                          hb + 3 * 65536, hb + 3 * 65536 + 32768, nullptr, 0, mbase + 1536, slot, red);
  phase_barrier(cnt, (++ep) * 256);

  // ---- finals: hf0,hb0,hf1,hb1 -> d_out (state in buf0 after 512 steps) ----
  {
    const int i = gtid;                 // 65536 values exactly
    const int dl = i >> 14, idx = i & 16383;
    const u16* hh = hb + dl * 65536;
    const u16* hl = hh + 32768;
    const float v = bf2f(hh[idx]) + bf2f(hl[idx]);
    const int base = 8192 + ((dl & 1) ? 32768 : 0) + ((dl >> 1) ? 16384 : 0);
    out[base + idx] = v;
  }
  // ---- FC: logits = [hf1|hb1] @ Wfc + bfc ----
  if (bid < 32) {
    const int gid = gtid;
    const int b = gid >> 8, o = gid & 255;
    const u16* f1h = hb + 2 * 65536; const u16* f1l = f1h + 32768;
    const u16* b1h = hb + 3 * 65536; const u16* b1l = b1h + 32768;
    float a = bfc[o];
    for (int k = 0; k < 512; ++k)
      a += (bf2f(f1h[b * 512 + k]) + bf2f(f1l[b * 512 + k])) * Wfc[(size_t)k * 256 + o];
    for (int k = 0; k < 512; ++k)
      a += (bf2f(b1h[b * 512 + k]) + bf2f(b1l[b * 512 + k])) * Wfc[(size_t)(512 + k) * 256 + o];
    out[gid] = a;
  }
}

extern "C" void kernel_launch(void* const* d_in, const int* in_sizes, int n_in,
                              void* d_out, int out_size, void* d_ws, size_t ws_size,
                              hipStream_t stream) {
  (void)in_sizes; (void)n_in; (void)out_size; (void)ws_size;
  const float* x   = (const float*)d_in[0];
  const float* Wf0 = (const float*)d_in[1];
  const float* bf0 = (const float*)d_in[2];
  const float* Wb0 = (const float*)d_in[3];
  const float* bb0 = (const float*)d_in[4];
  const float* Wf1 = (const float*)d_in[5];
  const float* bf1 = (const float*)d_in[6];
  const float* Wb1 = (const float*)d_in[7];
  const float* bb1 = (const float*)d_in[8];
  const float* Wfc = (const float*)d_in[9];
  const float* bfc = (const float*)d_in[10];
  rnn_init<<<1, 256, 0, stream>>>((u32*)d_ws);
  rnn_main<<<256, 256, 0, stream>>>(x, Wf0, bf0, Wb0, bb0, Wf1, bf1, Wb1, bb1,
                                    Wfc, bfc, (float*)d_out, (char*)d_ws);
}

// Round 6
// 3880.757 us; speedup vs baseline: 3.7109x; 1.4169x over previous
//
#include <hip/hip_runtime.h>

// BidirectionalRNN on MI355X — round 6: hardened XCD-local recurrence.
// vs round 5 (timed out): (1) election computed by bid0 only and published
// via coherent-point store + extra barrier (no divergent views possible);
// (2) step tags are global_atomic_add (L1-proof): no sc1 -> executes in the
// XCD's own L2 (intra-XCD coherent, cheap), sc1 in fallback mode;
// (3) deadman budgets on every poll loop -> worst case is a fast wrong
// answer with counters, never a 600s timeout.

typedef unsigned short u16;
typedef unsigned int u32;
typedef __attribute__((ext_vector_type(8))) short short8;
typedef __attribute__((ext_vector_type(4))) float f32x4;
typedef __attribute__((ext_vector_type(2))) unsigned int u32x2;

#define DEV static __device__ __forceinline__

DEV u16 f2bf(float f) {                       // f32 -> bf16 RNE
  u32 u = __builtin_bit_cast(u32, f);
  u = (u + 0x7fffu + ((u >> 16) & 1u)) >> 16;
  return (u16)u;
}
DEV float bf2f(u16 h) { return __builtin_bit_cast(float, ((u32)h) << 16); }

DEV f32x4 MFMA(short8 a, short8 b, f32x4 c) {
  return __builtin_amdgcn_mfma_f32_16x16x32_bf16(a, b, c, 0, 0, 0);
}

DEV float fast_tanh(float x) {                // (e^2x-1)/(e^2x+1) via v_exp+v_rcp
  float e = exp2f(x * 2.885390082f);
  return 1.0f - 2.0f * __builtin_amdgcn_rcpf(e + 1.0f);
}

// ---- data access helpers ----
DEV short8 ld_b128_coh(const u16* p) {        // sc0 sc1: coherent point
  short8 r;
  asm volatile("global_load_dwordx4 %0, %1, off sc0 sc1" : "=v"(r) : "v"(p) : "memory");
  return r;
}
DEV short8 ld_b128_l2(const u16* p) {         // sc0: L1-bypass, XCD-L2 hit
  short8 r;
  asm volatile("global_load_dwordx4 %0, %1, off sc0" : "=v"(r) : "v"(p) : "memory");
  return r;
}
DEV f32x4 ld_f32x4_vm(const float* p) {       // plain cached load, asm-ordered
  f32x4 r;
  asm volatile("global_load_dwordx4 %0, %1, off" : "=v"(r) : "v"(p) : "memory");
  return r;
}
DEV u32 ld_u32_coh(const u32* p) {
  u32 r;
  asm volatile("global_load_dword %0, %1, off sc0 sc1\n\ts_waitcnt vmcnt(0)"
               : "=v"(r) : "v"(p) : "memory");
  return r;
}
DEV void st_b64_coh(u16* p, u32x2 v) {
  asm volatile("global_store_dwordx2 %0, %1, off sc0 sc1" :: "v"(p), "v"(v) : "memory");
}
DEV void st_b64_l2(u16* p, u32x2 v) {
  asm volatile("global_store_dwordx2 %0, %1, off sc0" :: "v"(p), "v"(v) : "memory");
}
DEV void st_u32_coh(u32* p, u32 v) {
  asm volatile("global_store_dword %0, %1, off sc0 sc1" :: "v"(p), "v"(v) : "memory");
}
DEV void vm_drain() { asm volatile("s_waitcnt vmcnt(0)" ::: "memory"); }

// ---- tag sync via hardware atomics (never cached in L1) ----
// LOCAL: no sc1 -> executes in this XCD's L2 (intra-XCD coherent, fast).
// !LOCAL: sc1 -> executes at the device coherent point.
template<bool LOCAL>
DEV u32 tag_poll(u32* p) {                    // returns current value (add 0, sc0 = return old)
  u32 r; u32 z = 0;
  if (LOCAL)
    asm volatile("global_atomic_add %0, %1, %2, off sc0\n\ts_waitcnt vmcnt(0)"
                 : "=v"(r) : "v"(p), "v"(z) : "memory");
  else
    asm volatile("global_atomic_add %0, %1, %2, off sc0 sc1\n\ts_waitcnt vmcnt(0)"
                 : "=v"(r) : "v"(p), "v"(z) : "memory");
  return r;
}
template<bool LOCAL>
DEV void tag_post(u32* p) {                   // mem += 1, no return
  u32 one = 1;
  if (LOCAL)
    asm volatile("global_atomic_add %0, %1, off" :: "v"(p), "v"(one) : "memory");
  else
    asm volatile("global_atomic_add %0, %1, off sc1" :: "v"(p), "v"(one) : "memory");
}

// ---------------- ws layout (bytes) ----------------
constexpr size_t OFF_CNT  = 0;                       // [0]=phase ctr; [128..135]=claims; [160]=election
constexpr size_t OFF_MB   = 1024;                    // u32 base; region r at +r*1024 u32
constexpr size_t OFF_WT0F = 32768;
constexpr size_t NE_WT0   = 512 * 1024;              // W^T [512][1024] per plane
constexpr size_t SZ_WT0   = NE_WT0 * 2 * 2;          // hi+lo
constexpr size_t OFF_WT0B = OFF_WT0F + SZ_WT0;
constexpr size_t OFF_WT1F = OFF_WT0B + SZ_WT0;
constexpr size_t NE_WT1   = 512 * 1536;              // W^T [512][1536]
constexpr size_t SZ_WT1   = NE_WT1 * 2 * 2;
constexpr size_t OFF_WT1B = OFF_WT1F + SZ_WT1;
constexpr size_t OFF_XWF  = OFF_WT1B + SZ_WT1;       // f32 [512][32][512]
constexpr size_t SZ_XW    = 16384ull * 512 * 4;
constexpr size_t OFF_XWB  = OFF_XWF + SZ_XW;
constexpr size_t OFF_Y0   = OFF_XWB + SZ_XW;         // f32 [512][32][1024]
constexpr size_t SZ_Y0    = 16384ull * 1024 * 4;
constexpr size_t OFF_H    = OFF_Y0 + SZ_Y0;          // 4 dl x (hi b0,b1 | lo b0,b1) x 16384 u16

// Phase barrier: ONE release RMW + relaxed poll + ONE acquire fence per WG.
// Deadman-capped: never hangs forever.
DEV void phase_barrier(u32* c, u32 target) {
  __syncthreads();
  if (threadIdx.x == 0) {
    __hip_atomic_fetch_add(c, 1u, __ATOMIC_RELEASE, __HIP_MEMORY_SCOPE_AGENT);
    int spins = 0;
    while (__hip_atomic_load(c, __ATOMIC_RELAXED, __HIP_MEMORY_SCOPE_AGENT) < target) {
      __builtin_amdgcn_s_sleep(32);
      if (++spins > (1 << 20)) break;          // deadman
    }
    __builtin_amdgcn_fence(__ATOMIC_ACQUIRE, "agent");
  }
  __syncthreads();
}

// ---------------- projection GEMM: C[16384][512] = A[16384][K] @ W + bias ----------------
DEV void proj_phase(const float* __restrict__ A, bool perm, int bpitch, int bkoff, int K,
                    const u16* __restrict__ wfh, const u16* __restrict__ wfl,
                    const u16* __restrict__ wbh, const u16* __restrict__ wbl,
                    const float* __restrict__ biasF, const float* __restrict__ biasB,
                    float* __restrict__ Cf, float* __restrict__ Cb,
                    u16* aHi, u16* aLo, u16* bHi, u16* bLo) {
  const int tid = threadIdx.x;
  const int l = tid & 63, w = tid >> 6;
  const int lr = l & 15, lk = (l >> 4) * 8;
  const int wm = (w >> 1) * 64, wn = (w & 1) * 64;
  for (int t = blockIdx.x; t < 1024; t += 256) {
    const int dir = t >> 9, tile = t & 511;
    const int mbase = (tile >> 2) * 128, nbase = (tile & 3) * 128;
    const u16* bh_src = dir ? wbh : wfh;
    const u16* bl_src = dir ? wbl : wfl;
    const float* bias = dir ? biasB : biasF;
    float* C = dir ? Cb : Cf;
    f32x4 acc[4][4] = {};
    for (int kk = 0; kk < K; kk += 32) {
      {  // stage A (f32 -> hi/lo bf16) and B (pre-split) into LDS, [128][40] padded
        const int row = tid >> 1, half = tid & 1;
        const int r = mbase + row;
        const int srcRow = perm ? (((r & 31) << 9) + (r >> 5)) : r;
        const float* ap = A + (size_t)srcRow * K + kk + half * 16;
        f32x4 q0 = *(const f32x4*)(ap + 0);
        f32x4 q1 = *(const f32x4*)(ap + 4);
        f32x4 q2 = *(const f32x4*)(ap + 8);
        f32x4 q3 = *(const f32x4*)(ap + 12);
        short8 h0, l0, h1, l1;
        #pragma unroll
        for (int e = 0; e < 4; ++e) {
          { float v = q0[e]; u16 hv = f2bf(v); h0[e]   = (short)hv; l0[e]   = (short)f2bf(v - bf2f(hv)); }
          { float v = q1[e]; u16 hv = f2bf(v); h0[e+4] = (short)hv; l0[e+4] = (short)f2bf(v - bf2f(hv)); }
          { float v = q2[e]; u16 hv = f2bf(v); h1[e]   = (short)hv; l1[e]   = (short)f2bf(v - bf2f(hv)); }
          { float v = q3[e]; u16 hv = f2bf(v); h1[e+4] = (short)hv; l1[e+4] = (short)f2bf(v - bf2f(hv)); }
        }
        const int o = row * 40 + half * 16;
        *(short8*)&aHi[o] = h0; *(short8*)&aHi[o + 8] = h1;
        *(short8*)&aLo[o] = l0; *(short8*)&aLo[o + 8] = l1;
        const size_t bo = (size_t)(nbase + row) * bpitch + bkoff + kk + half * 16;
        *(short8*)&bHi[o]     = *(const short8*)&bh_src[bo];
        *(short8*)&bHi[o + 8] = *(const short8*)&bh_src[bo + 8];
        *(short8*)&bLo[o]     = *(const short8*)&bl_src[bo];
        *(short8*)&bLo[o + 8] = *(const short8*)&bl_src[bo + 8];
      }
      __syncthreads();
      short8 afh[4], afl[4], bfh[4], bfl[4];
      #pragma unroll
      for (int i = 0; i < 4; ++i) {
        afh[i] = *(short8*)&aHi[(wm + i * 16 + lr) * 40 + lk];
        afl[i] = *(short8*)&aLo[(wm + i * 16 + lr) * 40 + lk];
        bfh[i] = *(short8*)&bHi[(wn + i * 16 + lr) * 40 + lk];
        bfl[i] = *(short8*)&bLo[(wn + i * 16 + lr) * 40 + lk];
      }
      #pragma unroll
      for (int i = 0; i < 4; ++i)
        #pragma unroll
        for (int j = 0; j < 4; ++j) {
          acc[i][j] = MFMA(afh[i], bfh[j], acc[i][j]);
          acc[i][j] = MFMA(afh[i], bfl[j], acc[i][j]);
          acc[i][j] = MFMA(afl[i], bfh[j], acc[i][j]);
        }
      __syncthreads();
    }
    #pragma unroll
    for (int i = 0; i < 4; ++i)
      #pragma unroll
      for (int j = 0; j < 4; ++j) {
        const int gcol = nbase + wn + j * 16 + lr;
        const float bv = bias[gcol];
        #pragma unroll
        for (int rr = 0; rr < 4; ++rr) {
          const int grow = mbase + wm + i * 16 + (l >> 4) * 4 + rr;
          C[(size_t)grow * 512 + gcol] = acc[i][j][rr] + bv;
        }
      }
  }
}

// ---------------- recurrence: 512 steps of h = tanh(xw[s] + h @ Wh) ----------------
// 16 WGs per direction; WG `wgslot` owns cols [wgslot*32,+32). Wave w K-chunk
// [w*128,+128). Swapped-operand MFMA (lane = out-row, 4 consecutive out-cols
// per acc reg). Tags: atomic counters, consumer line c polls its own 64 slots.
template<bool LOCAL>
DEV void recurrence(bool fwd, const float* __restrict__ xw,
                    const u16* __restrict__ wtHi, const u16* __restrict__ wtLo,
                    int wpitch, int wkoff,
                    u16* __restrict__ hHi, u16* __restrict__ hLo,
                    float* __restrict__ y0, int ycol0,
                    u32* mb, int wgslot, float* red) {
  const int tid = threadIdx.x;
  const int l = tid & 63, w = tid >> 6;
  const int lr = l & 15, lk4 = l >> 4;
  const int c0 = wgslot * 32;
  short8 wfh[2][4], wfl[2][4];
  #pragma unroll
  for (int ct = 0; ct < 2; ++ct)
    #pragma unroll
    for (int ks = 0; ks < 4; ++ks) {
      const size_t o = (size_t)(c0 + ct * 16 + lr) * wpitch + wkoff + w * 128 + ks * 32 + lk4 * 8;
      wfh[ct][ks] = *(const short8*)&wtHi[o];
      wfl[ct][ks] = *(const short8*)&wtLo[o];
    }
  const int frow = (w & 1) * 16 + lr;
  const int fcb  = c0 + (w >> 1) * 16 + lk4 * 4;
  const u32 mySlot = (u32)(wgslot * 4 + w);
  u32* pollp = mb + wgslot * 64 + l;
  int budget = 1 << 22;                        // deadman: whole-recurrence poll budget
  for (int t = 0; t < 512; ++t) {
    const int s = fwd ? t : (511 - t);
    f32x4 xwv = ld_f32x4_vm(xw + (size_t)(s * 32 + frow) * 512 + fcb);
    if (t) {
      for (;;) {
        u32 v = tag_poll<LOCAL>(pollp);
        if (__all((int)(v >= (u32)t))) break;
        if (--budget < 0) break;               // deadman: proceed (fails fast, no hang)
      }
    }
    const u16* hh = hHi + (t & 1) * 16384;
    const u16* hl = hLo + (t & 1) * 16384;
    u16* nhh = hHi + ((t & 1) ^ 1) * 16384;
    u16* nhl = hLo + ((t & 1) ^ 1) * 16384;
    short8 hfh0[4], hfl0[4], hfh1[4], hfl1[4];
    #pragma unroll
    for (int g = 0; g < 4; ++g) {
      const int k = w * 128 + g * 32 + lk4 * 8;
      if (LOCAL) {
        hfh0[g] = ld_b128_l2(&hh[lr * 512 + k]);
        hfl0[g] = ld_b128_l2(&hl[lr * 512 + k]);
        hfh1[g] = ld_b128_l2(&hh[(16 + lr) * 512 + k]);
        hfl1[g] = ld_b128_l2(&hl[(16 + lr) * 512 + k]);
      } else {
        hfh0[g] = ld_b128_coh(&hh[lr * 512 + k]);
        hfl0[g] = ld_b128_coh(&hl[lr * 512 + k]);
        hfh1[g] = ld_b128_coh(&hh[(16 + lr) * 512 + k]);
        hfl1[g] = ld_b128_coh(&hl[(16 + lr) * 512 + k]);
      }
    }
    f32x4 acc[2][2] = {};
    #pragma unroll
    for (int g = 0; g < 4; ++g) {
      if (g == 0)      asm volatile("s_waitcnt vmcnt(12)" ::: "memory");
      else if (g == 1) asm volatile("s_waitcnt vmcnt(8)"  ::: "memory");
      else if (g == 2) asm volatile("s_waitcnt vmcnt(4)"  ::: "memory");
      else             asm volatile("s_waitcnt vmcnt(0)"  ::: "memory");
      __builtin_amdgcn_sched_barrier(0);
      #pragma unroll
      for (int ct = 0; ct < 2; ++ct) {
        acc[ct][0] = MFMA(wfh[ct][g], hfh0[g], acc[ct][0]);
        acc[ct][0] = MFMA(wfh[ct][g], hfl0[g], acc[ct][0]);
        acc[ct][0] = MFMA(wfl[ct][g], hfh0[g], acc[ct][0]);
        acc[ct][1] = MFMA(wfh[ct][g], hfh1[g], acc[ct][1]);
        acc[ct][1] = MFMA(wfh[ct][g], hfl1[g], acc[ct][1]);
        acc[ct][1] = MFMA(wfl[ct][g], hfh1[g], acc[ct][1]);
      }
    }
    #pragma unroll
    for (int ct = 0; ct < 2; ++ct)
      #pragma unroll
      for (int rh = 0; rh < 2; ++rh)
        *(f32x4*)&red[((w * 4 + ct * 2 + rh) * 64 + l) * 4] = acc[ct][rh];
    __syncthreads();
    f32x4 fin = xwv;
    #pragma unroll
    for (int wp = 0; wp < 4; ++wp)
      fin += *(const f32x4*)&red[((wp * 4 + w) * 64 + l) * 4];
    f32x4 tv;
    #pragma unroll
    for (int rr = 0; rr < 4; ++rr) tv[rr] = fast_tanh(fin[rr]);
    u32x2 hw, lw;
    {
      u16 hv[4], lv[4];
      #pragma unroll
      for (int i = 0; i < 4; ++i) { hv[i] = f2bf(tv[i]); lv[i] = f2bf(tv[i] - bf2f(hv[i])); }
      hw[0] = (u32)hv[0] | ((u32)hv[1] << 16); hw[1] = (u32)hv[2] | ((u32)hv[3] << 16);
      lw[0] = (u32)lv[0] | ((u32)lv[1] << 16); lw[1] = (u32)lv[2] | ((u32)lv[3] << 16);
    }
    if (LOCAL) {
      st_b64_l2(&nhh[frow * 512 + fcb], hw);
      st_b64_l2(&nhl[frow * 512 + fcb], lw);
    } else {
      st_b64_coh(&nhh[frow * 512 + fcb], hw);
      st_b64_coh(&nhl[frow * 512 + fcb], lw);
    }
    vm_drain();                        // h committed before tags move
    if (l < 16) tag_post<LOCAL>(mb + l * 64 + mySlot);   // post to 16 consumer lines
    if (y0)                            // off critical path; flushed at phase barrier
      *(f32x4*)&y0[(size_t)(s * 32 + frow) * 1024 + ycol0 + fcb] = tv;
  }
}

__global__ void rnn_init(u32* c) {            // zero counters + claims + mailboxes (32KB)
  #pragma unroll
  for (int i = 0; i < 8; ++i) c[threadIdx.x * 8 + i] = 0;
}

__global__ __launch_bounds__(256, 1) void rnn_main(
    const float* __restrict__ x,
    const float* __restrict__ Wf0, const float* __restrict__ bf0,
    const float* __restrict__ Wb0, const float* __restrict__ bb0,
    const float* __restrict__ Wf1, const float* __restrict__ bf1,
    const float* __restrict__ Wb1, const float* __restrict__ bb1,
    const float* __restrict__ Wfc, const float* __restrict__ bfc,
    float* __restrict__ out, char* __restrict__ ws) {
  __shared__ __align__(16) u16 lds[20480];          // 40 KB: proj tiles / rec reduce
  u16* aHi = lds; u16* aLo = lds + 5120; u16* bHi = lds + 10240; u16* bLo = lds + 15360;
  float* red = (float*)lds;
  __shared__ u32 sh_xcd, sh_slot, sh_el;

  u32* cnt = (u32*)(ws + OFF_CNT);
  u32* mbase = (u32*)(ws + OFF_MB);
  u16* wt0f_hi = (u16*)(ws + OFF_WT0F); u16* wt0f_lo = wt0f_hi + NE_WT0;
  u16* wt0b_hi = (u16*)(ws + OFF_WT0B); u16* wt0b_lo = wt0b_hi + NE_WT0;
  u16* wt1f_hi = (u16*)(ws + OFF_WT1F); u16* wt1f_lo = wt1f_hi + NE_WT1;
  u16* wt1b_hi = (u16*)(ws + OFF_WT1B); u16* wt1b_lo = wt1b_hi + NE_WT1;
  float* xwf = (float*)(ws + OFF_XWF);
  float* xwb = (float*)(ws + OFF_XWB);
  float* y0  = (float*)(ws + OFF_Y0);
  u16* hb = (u16*)(ws + OFF_H);

  const int gtid = blockIdx.x * 256 + threadIdx.x;
  const int bid = blockIdx.x;

  // ---- claim a slot on our physical XCD ----
  if (threadIdx.x == 0) {
    u32 xcd;
    asm volatile("s_getreg_b32 %0, hwreg(HW_REG_XCC_ID)" : "=s"(xcd));
    xcd &= 7u;
    sh_xcd = xcd;
    sh_slot = __hip_atomic_fetch_add(&cnt[128 + xcd], 1u, __ATOMIC_RELAXED,
                                     __HIP_MEMORY_SCOPE_AGENT);
  }
  __syncthreads();
  const u32 myXcd = sh_xcd, mySlotIdx = sh_slot;

  // ---- init: split+transpose weights, zero h state ----
  for (u32 j = gtid; j < (u32)NE_WT0; j += 65536u) {
    const u32 n = j >> 10, r = j & 1023;
    float v = Wf0[(size_t)r * 512 + n];
    u16 hv = f2bf(v); wt0f_hi[j] = hv; wt0f_lo[j] = f2bf(v - bf2f(hv));
    v = Wb0[(size_t)r * 512 + n];
    hv = f2bf(v); wt0b_hi[j] = hv; wt0b_lo[j] = f2bf(v - bf2f(hv));
  }
  for (u32 j = gtid; j < (u32)NE_WT1; j += 65536u) {
    const u32 n = j / 1536u, r = j - n * 1536u;
    float v = Wf1[(size_t)r * 512 + n];
    u16 hv = f2bf(v); wt1f_hi[j] = hv; wt1f_lo[j] = f2bf(v - bf2f(hv));
    v = Wb1[(size_t)r * 512 + n];
    hv = f2bf(v); wt1b_hi[j] = hv; wt1b_lo[j] = f2bf(v - bf2f(hv));
  }
  for (u32 j = gtid; j < 131072u; j += 65536u) ((u32*)hb)[j] = 0;

  u32 ep = 0;
  phase_barrier(cnt, (++ep) * 256);           // #1: claims + init complete

  // ---- election: single source (bid 0), published via coherent point ----
  if (bid == 0 && threadIdx.x == 0) {
    u32 cv[8];
    for (int i = 0; i < 8; ++i) cv[i] = ld_u32_coh(&cnt[128 + i]);
    int fwdX = 0;
    for (int i = 1; i < 8; ++i) if (cv[i] > cv[fwdX]) fwdX = i;
    int bwdX = (fwdX == 0) ? 1 : 0;
    for (int i = 0; i < 8; ++i) if (i != fwdX && cv[i] > cv[bwdX]) bwdX = i;
    u32 ok = (cv[fwdX] >= 16 && cv[bwdX] >= 16) ? 1u : 0u;
    st_u32_coh(&cnt[160], (u32)fwdX | ((u32)bwdX << 4) | (ok << 8));
    vm_drain();
  }
  phase_barrier(cnt, (++ep) * 256);           // #2: election published
  if (threadIdx.x == 0) sh_el = ld_u32_coh(&cnt[160]);
  __syncthreads();
  const u32 el = sh_el;
  const int fwdX = (int)(el & 15), bwdX = (int)((el >> 4) & 15);
  const bool useLocal = ((el >> 8) & 1) != 0;

  bool rf, rb; int slot;
  if (useLocal) {
    rf = ((int)myXcd == fwdX) && (mySlotIdx < 16);
    rb = ((int)myXcd == bwdX) && (mySlotIdx < 16);
    slot = (int)mySlotIdx;
  } else {
    rf = bid < 16;
    rb = bid >= 16 && bid < 32;
    slot = bid & 15;
  }

  // ---- layer-0 input projection ----
  proj_phase(x, true, 1024, 0, 512, wt0f_hi, wt0f_lo, wt0b_hi, wt0b_lo,
             bf0, bb0, xwf, xwb, aHi, aLo, bHi, bLo);
  phase_barrier(cnt, (++ep) * 256);           // #3

  // ---- layer-0 recurrence (fwd || bwd), writes y0 ----
  if (rf) {
    if (useLocal) recurrence<true >(true,  xwf, wt0f_hi, wt0f_lo, 1024, 512,
                    hb + 0 * 65536, hb + 0 * 65536 + 32768, y0, 0,   mbase,        slot, red);
    else          recurrence<false>(true,  xwf, wt0f_hi, wt0f_lo, 1024, 512,
                    hb + 0 * 65536, hb + 0 * 65536 + 32768, y0, 0,   mbase,        slot, red);
  } else if (rb) {
    if (useLocal) recurrence<true >(false, xwb, wt0b_hi, wt0b_lo, 1024, 512,
                    hb + 1 * 65536, hb + 1 * 65536 + 32768, y0, 512, mbase + 1024, slot, red);
    else          recurrence<false>(false, xwb, wt0b_hi, wt0b_lo, 1024, 512,
                    hb + 1 * 65536, hb + 1 * 65536 + 32768, y0, 512, mbase + 1024, slot, red);
  }
  phase_barrier(cnt, (++ep) * 256);           // #4

  // ---- layer-1 input projection (A = y0, K=1024) ----
  proj_phase(y0, false, 1536, 0, 1024, wt1f_hi, wt1f_lo, wt1b_hi, wt1b_lo,
             bf1, bb1, xwf, xwb, aHi, aLo, bHi, bLo);
  phase_barrier(cnt, (++ep) * 256);           // #5

  // ---- layer-1 recurrence ----
  if (rf) {
    if (useLocal) recurrence<true >(true,  xwf, wt1f_hi, wt1f_lo, 1536, 1024,
                    hb + 2 * 65536, hb + 2 * 65536 + 32768, nullptr, 0, mbase + 2048, slot, red);
    else          recurrence<false>(true,  xwf, wt1f_hi, wt1f_lo, 1536, 1024,
                    hb + 2 * 65536, hb + 2 * 65536 + 32768, nullptr, 0, mbase + 2048, slot, red);
  } else if (rb) {
    if (useLocal) recurrence<true >(false, xwb, wt1b_hi, wt1b_lo, 1536, 1024,
                    hb + 3 * 65536, hb + 3 * 65536 + 32768, nullptr, 0, mbase + 3072, slot, red);
    else          recurrence<false>(false, xwb, wt1b_hi, wt1b_lo, 1536, 1024,
                    hb + 3 * 65536, hb + 3 * 65536 + 32768, nullptr, 0, mbase + 3072, slot, red);
  }
  phase_barrier(cnt, (++ep) * 256);           // #6

  // ---- finals: hf0,hb0,hf1,hb1 -> d_out (state in buf0 after 512 steps) ----
  {
    const int i = gtid;                 // 65536 values exactly
    const int dl = i >> 14, idx = i & 16383;
    const u16* hh = hb + dl * 65536;
    const u16* hl = hh + 32768;
    const float v = bf2f(hh[idx]) + bf2f(hl[idx]);
    const int base = 8192 + ((dl & 1) ? 32768 : 0) + ((dl >> 1) ? 16384 : 0);
    out[base + idx] = v;
  }
  // ---- FC: logits = [hf1|hb1] @ Wfc + bfc ----
  if (bid < 32) {
    const int gid = gtid;
    const int b = gid >> 8, o = gid & 255;
    const u16* f1h = hb + 2 * 65536; const u16* f1l = f1h + 32768;
    const u16* b1h = hb + 3 * 65536; const u16* b1l = b1h + 32768;
    float a = bfc[o];
    for (int k = 0; k < 512; ++k)
      a += (bf2f(f1h[b * 512 + k]) + bf2f(f1l[b * 512 + k])) * Wfc[(size_t)k * 256 + o];
    for (int k = 0; k < 512; ++k)
      a += (bf2f(b1h[b * 512 + k]) + bf2f(b1l[b * 512 + k])) * Wfc[(size_t)(512 + k) * 256 + o];
    out[gid] = a;
  }
}

extern "C" void kernel_launch(void* const* d_in, const int* in_sizes, int n_in,
                              void* d_out, int out_size, void* d_ws, size_t ws_size,
                              hipStream_t stream) {
  (void)in_sizes; (void)n_in; (void)out_size; (void)ws_size;
  const float* x   = (const float*)d_in[0];
  const float* Wf0 = (const float*)d_in[1];
  const float* bf0 = (const float*)d_in[2];
  const float* Wb0 = (const float*)d_in[3];
  const float* bb0 = (const float*)d_in[4];
  const float* Wf1 = (const float*)d_in[5];
  const float* bf1 = (const float*)d_in[6];
  const float* Wb1 = (const float*)d_in[7];
  const float* bb1 = (const float*)d_in[8];
  const float* Wfc = (const float*)d_in[9];
  const float* bfc = (const float*)d_in[10];
  rnn_init<<<1, 1024, 0, stream>>>((u32*)d_ws);
  rnn_main<<<256, 256, 0, stream>>>(x, Wf0, bf0, Wb0, bb0, Wf1, bf1, Wb1, bb1,
                                    Wfc, bfc, (float*)d_out, (char*)d_ws);
}